// Round 3
// baseline (512.183 us; speedup 1.0000x reference)
//
#include <hip/hip_runtime.h>
#include <math.h>

// ---------------- workspace layout (bytes) ----------------
#define X_B      0         // 512*1024 f32 = 2,097,152
#define BBOX_B   2097152   // 36*1024 f32  = 147,456
#define PROPS_B  2244608   // 9216 float4  = 147,456
#define KEYS_B   2392064   // 9216 u64     = 73,728
#define RANK_B   2465792   // 9216 u32     = 36,864
#define SKEYS_B  2502656   // 9216 u64     = 73,728
#define SBOX_B   2576384   // 9216 float4  = 147,456  (end 2,723,840)

// ================= conv 3x3 (256->512, 32x32, pad 1) + ReLU =================
// 512 blocks = (channel-pair cp, image-half h). 256 threads: thread = 1 row x
// 2 cols x 2 channels (4 fp64 accs). Input tile (8ch x 18rows x pitch38 fp32)
// in LDS with zero halo; WEIGHTS VIA SCALAR LOADS (uniform index -> s_load,
// no LDS/ds traffic). fp64 accumulation (NMS decisions need near-exactness).
#define CPITCH 38
#define CCHS   (18 * CPITCH)           // 684 floats per channel slice

__global__ __launch_bounds__(256) void conv3x3_relu_k(
    const float* __restrict__ feat, const float* __restrict__ w,
    const float* __restrict__ bias, float* __restrict__ xout)
{
  __shared__ float il[8 * CCHS];       // 21,888 B
  const int cp = blockIdx.x >> 1, h = blockIdx.x & 1;
  const int tid = threadIdx.x;
  const int h16 = h << 4;
  const int co0 = cp << 1;
  for (int i = tid; i < 8 * CCHS; i += 256) il[i] = 0.0f;   // halo zeros

  const int yl = tid >> 4;             // 0..15  local row
  const int x0 = (tid & 15) << 1;      // 0..30
  double aA0 = 0.0, aA1 = 0.0, aB0 = 0.0, aB1 = 0.0;

  const float4* feat4 = (const float4*)feat;
  // staging: 8ch x 18rows x 8 float4 = 1152 float4 -> 5 predicated per thread
  float4 pf[5];
  int pch[5], pt[5], pc4[5], pok[5];
  #pragma unroll
  for (int k = 0; k < 5; ++k) {
    const int i = tid + (k << 8);
    const int ch = i / 144, rem = i - ch * 144;
    const int t = rem >> 3, c4 = rem & 7;
    const int g = h16 - 1 + t;
    pch[k] = ch; pt[k] = t; pc4[k] = c4;
    pok[k] = (i < 1152) && ((unsigned)g < 32u);
    pf[k] = pok[k] ? feat4[(ch << 8) + (g << 3) + c4] : float4{0.f,0.f,0.f,0.f};
  }

  for (int cc = 0; cc < 256; cc += 8) {
    __syncthreads();
    #pragma unroll
    for (int k = 0; k < 5; ++k) {
      if (pok[k]) {
        float* p = &il[pch[k] * CCHS + pt[k] * CPITCH + (pc4[k] << 2) + 1];
        p[0] = pf[k].x; p[1] = pf[k].y; p[2] = pf[k].z; p[3] = pf[k].w;
      }
    }
    __syncthreads();
    if (cc + 8 < 256) {
      #pragma unroll
      for (int k = 0; k < 5; ++k) {
        const int g = h16 - 1 + pt[k];
        if (pok[k]) pf[k] = feat4[((cc + 8 + pch[k]) << 8) + (g << 3) + pc4[k]];
      }
    }
    #pragma unroll
    for (int cl = 0; cl < 8; ++cl) {
      const int ci = cc + cl;
      const float* wA = w + co0 * 2304 + ci * 9;       // uniform -> s_load
      const float* wB = wA + 2304;
      const float* ir = &il[cl * CCHS + yl * CPITCH + x0];
      #pragma unroll
      for (int ky = 0; ky < 3; ++ky) {
        const float2 q0 = *(const float2*)(ir + ky * CPITCH);
        const float2 q1 = *(const float2*)(ir + ky * CPITCH + 2);
        const double v0 = (double)q0.x, v1 = (double)q0.y;
        const double v2 = (double)q1.x, v3 = (double)q1.y;
        const double wa0 = (double)wA[3*ky+0], wa1 = (double)wA[3*ky+1], wa2 = (double)wA[3*ky+2];
        const double wb0 = (double)wB[3*ky+0], wb1 = (double)wB[3*ky+1], wb2 = (double)wB[3*ky+2];
        aA0 += v0 * wa0 + v1 * wa1 + v2 * wa2;
        aA1 += v1 * wa0 + v2 * wa1 + v3 * wa2;
        aB0 += v0 * wb0 + v1 * wb1 + v2 * wb2;
        aB1 += v1 * wb0 + v2 * wb1 + v3 * wb2;
      }
    }
  }
  const double bA = (double)bias[co0], bB = (double)bias[co0 + 1];
  const int y = h16 + yl;
  float2 rA, rB;
  rA.x = (float)fmax(aA0 + bA, 0.0); rA.y = (float)fmax(aA1 + bA, 0.0);
  rB.x = (float)fmax(aB0 + bB, 0.0); rB.y = (float)fmax(aB1 + bB, 0.0);
  *(float2*)&xout[(co0 << 10) + (y << 5) + x0] = rA;
  *(float2*)&xout[((co0 + 1) << 10) + (y << 5) + x0] = rB;
}

// ================= 1x1 heads: cls (18ch -> sigmoid -> out) + bbox (36ch) ====
__global__ __launch_bounds__(256) void head1x1_k(
    const float* __restrict__ x,
    const float* __restrict__ cls_w, const float* __restrict__ cls_b,
    const float* __restrict__ bbox_w, const float* __restrict__ bbox_b,
    float* __restrict__ out, float* __restrict__ bbox_out)
{
  __shared__ float wl[512];
  const int bid = blockIdx.x;
  const int co = bid >> 2;                       // 0..53
  const int px = ((bid & 3) << 8) | threadIdx.x; // 0..1023
  const bool is_cls = co < 18;
  const float* wsrc = is_cls ? (cls_w + co * 512) : (bbox_w + (co - 18) * 512);
  for (int i = threadIdx.x; i < 512; i += 256) wl[i] = wsrc[i];
  __syncthreads();
  double acc0 = 0.0, acc1 = 0.0, acc2 = 0.0, acc3 = 0.0;
  #pragma unroll 4
  for (int c = 0; c < 512; c += 4) {
    acc0 += (double)x[((c + 0) << 10) | px] * (double)wl[c + 0];
    acc1 += (double)x[((c + 1) << 10) | px] * (double)wl[c + 1];
    acc2 += (double)x[((c + 2) << 10) | px] * (double)wl[c + 2];
    acc3 += (double)x[((c + 3) << 10) | px] * (double)wl[c + 3];
  }
  double acc = ((acc0 + acc1) + (acc2 + acc3)) +
               (double)(is_cls ? cls_b[co] : bbox_b[co - 18]);
  if (is_cls)
    out[36864 + (co << 10) + px] = (float)(1.0 / (1.0 + exp(-acc)));
  else
    bbox_out[((co - 18) << 10) + px] = (float)acc;
}

// ============ anchors + box decode + clip + key build + rank zero ===========
__global__ __launch_bounds__(256) void proposals_k(
    const float* __restrict__ bbox, const int* __restrict__ imgsz,
    const float* __restrict__ out, float* __restrict__ props,
    unsigned long long* __restrict__ keys, unsigned* __restrict__ rank)
{
  const int r = blockIdx.x * 256 + threadIdx.x;
  if (r >= 9216) return;
  const float4 d = ((const float4*)bbox)[r];
  const int cell = r / 9, a = r - cell * 9;
  const int ix = cell & 31, iy = cell >> 5;
  const int ri = a / 3, si = a - ri * 3;
  const double ratio = (ri == 0) ? 0.5 : (ri == 1 ? 1.0 : 2.0);
  const double scale = (si == 0) ? 128.0 : (si == 1 ? 256.0 : 512.0);
  const double hr = sqrt(ratio), wr = 1.0 / hr;
  const double bx = nearbyint(wr * scale * 0.5);
  const double by = nearbyint(hr * scale * 0.5);
  const double cx = ix * 16.0, cy = iy * 16.0;
  const double w = 2.0 * bx, hh = 2.0 * by;
  const double pcx = (double)d.x * w + cx;
  const double pcy = (double)d.y * hh + cy;
  const double pw = exp((double)d.z) * w;
  const double ph = exp((double)d.w) * hh;
  const double im = (double)imgsz[0];
  float4 o;
  o.x = (float)fmin(fmax(pcx - 0.5 * pw, 0.0), im);
  o.y = (float)fmin(fmax(pcy - 0.5 * ph, 0.0), im);
  o.z = (float)fmin(fmax(pcx + 0.5 * pw, 0.0), im);
  o.w = (float)fmin(fmax(pcy + 0.5 * ph, 0.0), im);
  ((float4*)props)[r] = o;
  // fg score (probs channel 2a+1), same flatten as reference
  const float s = out[36864 + ((2 * (r >> 10) + 1) << 10) + (r & 1023)];
  keys[r] = ((unsigned long long)__float_as_uint(s) << 32) |
            (unsigned)(0x7FFFFFFF - r);
  rank[r] = 0u;
}

// ================= rank sort: rank[j] = #{i : key_i > key_j} ================
// 288 blocks = 36 j-tiles x 8 i-chunks. Wave holds 1152 i-keys in regs;
// v_readlane broadcasts each to all lanes (no LDS/ds traffic).
__global__ __launch_bounds__(256) void rank_k(
    const unsigned long long* __restrict__ keys, unsigned* __restrict__ rank)
{
  const int jt = blockIdx.x % 36, ic = blockIdx.x / 36;
  const int j = jt * 256 + threadIdx.x;
  const unsigned long long kj = keys[j];
  const int lane = threadIdx.x & 63;
  const int base = ic * 1152;
  unsigned lo[18], hi[18];
  #pragma unroll
  for (int rr = 0; rr < 18; ++rr) {
    const unsigned long long k = keys[base + rr * 64 + lane];
    lo[rr] = (unsigned)k; hi[rr] = (unsigned)(k >> 32);
  }
  unsigned cnt = 0;
  #pragma unroll
  for (int rr = 0; rr < 18; ++rr) {
    #pragma unroll
    for (int l = 0; l < 64; ++l) {
      const unsigned llo = (unsigned)__builtin_amdgcn_readlane((int)lo[rr], l);
      const unsigned lhi = (unsigned)__builtin_amdgcn_readlane((int)hi[rr], l);
      const unsigned long long ki = ((unsigned long long)lhi << 32) | llo;
      cnt += (ki > kj) ? 1u : 0u;
    }
  }
  atomicAdd(&rank[j], cnt);
}

// ================= scatter into sorted order ================================
__global__ __launch_bounds__(256) void scatter_k(
    const unsigned long long* __restrict__ keys, const unsigned* __restrict__ rank,
    const float* __restrict__ props, unsigned long long* __restrict__ skeys,
    float4* __restrict__ sboxes)
{
  const int r = blockIdx.x * 256 + threadIdx.x;
  if (r >= 9216) return;
  const unsigned rk = rank[r];
  skeys[rk] = keys[r];
  sboxes[rk] = ((const float4*)props)[r];
}

// ================= exact sequential NMS, sorted + batched ===================
// Single block, 1024 threads, boxes pre-sorted by score desc (rank 0 = best).
// Wave0 batches up to 4 kept boxes per iteration: candidate = next alive rank;
// tested only against the current batch (earlier kept already applied) ->
// exact sequential semantics. All threads then suppress their 9 register
// boxes vs the batch. IoU decision identical to R2 (fp64 mul-compare).
__device__ __forceinline__ bool iou_gt(const float4 cb, const float4 b) {
  const float ix1 = fmaxf(b.x, cb.x), iy1 = fmaxf(b.y, cb.y);
  const float ix2 = fminf(b.z, cb.z), iy2 = fminf(b.w, cb.w);
  const float iw = fmaxf(ix2 - ix1, 0.0f), ih = fmaxf(iy2 - iy1, 0.0f);
  const float areaB = (b.z - b.x) * (b.w - b.y);
  const float areaC = (cb.z - cb.x) * (cb.w - cb.y);
  const double inter = (double)iw * (double)ih;
  const double uni = (double)areaB + (double)areaC - inter + 1e-9;
  return inter > 0.3 * uni;
}

__global__ __launch_bounds__(1024) void nms_k(
    const float4* __restrict__ sb4, const unsigned long long* __restrict__ skeys,
    float* __restrict__ out)
{
  extern __shared__ char smem[];
  float4* sbox = (float4*)smem;                                   // 147456
  unsigned long long* alive = (unsigned long long*)(smem + 147456); // 1152
  unsigned long long* keptw = (unsigned long long*)(smem + 148608); // 1152
  float4* sbb = (float4*)(smem + 149760);                         // 64
  int* sctl = (int*)(smem + 149824);                              // 2 ints

  const int tid = threadIdx.x;
  float4 box[9];
  #pragma unroll
  for (int j = 0; j < 9; ++j) box[j] = sb4[9 * tid + j];
  for (int i = tid; i < 9216; i += 1024) sbox[i] = sb4[i];
  if (tid < 144) { alive[tid] = ~0ULL; keptw[tid] = 0ULL; }
  __syncthreads();

  int cursor = 0;
  for (int iter = 0; iter < 9300; ++iter) {
    // ---- A: wave0, uniform redundant scan ----
    if (tid < 64) {
      int B = 0, scanned = 0, done = 0, nextcur = 9216;
      float4 bb[4];
      if (cursor >= 9216) done = 1;
      else {
        int w = cursor >> 6;
        unsigned long long cur = alive[w] & (~0ULL << (cursor & 63));
        while (B < 4 && scanned < 12) {
          while (cur == 0ULL) { ++w; if (w >= 144) break; cur = alive[w]; }
          if (w >= 144) break;
          const int bit = __builtin_ctzll(cur);
          cur &= cur - 1ULL;
          const int r = (w << 6) + bit;
          ++scanned;
          const float4 c = sbox[r];
          bool sup = false;
          for (int i = 0; i < B; ++i) sup = sup || iou_gt(bb[i], c);
          if (tid == 0) alive[w] &= ~(1ULL << bit);   // leaves alive either way
          if (!sup) {
            bb[B] = c;
            if (tid == 0) { keptw[w] |= (1ULL << bit); sbb[B] = c; }
            ++B;
          }
          nextcur = r + 1;
        }
        if (scanned == 0 && B == 0) done = 1;
        cursor = (scanned > 0) ? nextcur : 9216;
      }
      if (tid == 0) { sctl[0] = B; sctl[1] = done; }
    }
    __syncthreads();
    if (sctl[1]) break;
    // ---- D: all threads suppress their alive boxes vs batch ----
    const int Bn = sctl[0];
    if (Bn > 0) {
      float4 bl[4];
      #pragma unroll
      for (int i = 0; i < 4; ++i) if (i < Bn) bl[i] = sbb[i];
      const int w0 = (9 * tid) >> 6;
      const int w1 = ((9 * tid + 8) >> 6);
      const unsigned long long a0 = alive[w0];
      const unsigned long long a1 = alive[w1];
      unsigned long long cm0 = 0ULL, cm1 = 0ULL;
      #pragma unroll
      for (int j = 0; j < 9; ++j) {
        const int r = 9 * tid + j;
        const int hiw = (r >> 6) != w0;
        const unsigned long long abit = ((hiw ? a1 : a0) >> (r & 63)) & 1ULL;
        if (abit) {
          bool sup = false;
          for (int i = 0; i < Bn; ++i) sup = sup || iou_gt(bl[i], box[j]);
          if (sup) { if (hiw) cm1 |= 1ULL << (r & 63); else cm0 |= 1ULL << (r & 63); }
        }
      }
      if (cm0) atomicAnd(&alive[w0], ~cm0);
      if (cm1) atomicAnd(&alive[w1], ~cm1);
    }
    __syncthreads();
  }
  // ---- output ----
  const unsigned long long k0 = keptw[(9 * tid) >> 6];
  const unsigned long long k1 = keptw[(9 * tid + 8) >> 6];
  const int w0 = (9 * tid) >> 6;
  #pragma unroll
  for (int j = 0; j < 9; ++j) {
    const int r = 9 * tid + j;
    const bool kp = ((((r >> 6) != w0) ? k1 : k0) >> (r & 63)) & 1ULL;
    const unsigned long long key = skeys[r];
    const int orig = 0x7FFFFFFF - (int)(unsigned)(key & 0xFFFFFFFFULL);
    float4 ob = box[j];
    if (!kp) { ob.x = 0.f; ob.y = 0.f; ob.z = 0.f; ob.w = 0.f; }
    ((float4*)out)[orig] = ob;
    out[55296 + orig] = kp ? 1.0f : 0.0f;
  }
}

// ============================================================================
extern "C" void kernel_launch(void* const* d_in, const int* in_sizes, int n_in,
                              void* d_out, int out_size, void* d_ws, size_t ws_size,
                              hipStream_t stream)
{
  const float* feat   = (const float*)d_in[0];
  const int*   imgsz  = (const int*)d_in[1];
  const float* conv_w = (const float*)d_in[2];
  const float* conv_b = (const float*)d_in[3];
  const float* cls_w  = (const float*)d_in[4];
  const float* cls_b  = (const float*)d_in[5];
  const float* bbox_w = (const float*)d_in[6];
  const float* bbox_b = (const float*)d_in[7];
  float* out = (float*)d_out;
  char*  ws  = (char*)d_ws;
  float* x      = (float*)(ws + X_B);
  float* bbox   = (float*)(ws + BBOX_B);
  float* props  = (float*)(ws + PROPS_B);
  unsigned long long* keys  = (unsigned long long*)(ws + KEYS_B);
  unsigned*           rankp = (unsigned*)(ws + RANK_B);
  unsigned long long* skeys = (unsigned long long*)(ws + SKEYS_B);
  float4*             sboxs = (float4*)(ws + SBOX_B);

  hipLaunchKernelGGL(conv3x3_relu_k, dim3(512), dim3(256), 0, stream,
                     feat, conv_w, conv_b, x);
  hipLaunchKernelGGL(head1x1_k, dim3(216), dim3(256), 0, stream,
                     x, cls_w, cls_b, bbox_w, bbox_b, out, bbox);
  hipLaunchKernelGGL(proposals_k, dim3(36), dim3(256), 0, stream,
                     bbox, imgsz, out, props, keys, rankp);
  hipLaunchKernelGGL(rank_k, dim3(288), dim3(256), 0, stream, keys, rankp);
  hipLaunchKernelGGL(scatter_k, dim3(36), dim3(256), 0, stream,
                     keys, rankp, props, skeys, sboxs);
  hipLaunchKernelGGL(nms_k, dim3(1), dim3(1024), 149840, stream,
                     sboxs, skeys, out);
}

// Round 4
// 395.521 us; speedup vs baseline: 1.2950x; 1.2950x over previous
//
#include <hip/hip_runtime.h>
#include <math.h>

// ---------------- workspace layout (bytes) ----------------
#define X_B      0         // 512*1024 f32   = 2,097,152
#define BBOX_B   2097152   // 36*1024 f32    = 147,456
#define PROPS_B  2244608   // 9216 float4    = 147,456
#define KEYS_B   2392064   // 9216 u64       = 73,728
#define RANK_B   2465792   // 9216 u32       = 36,864
#define SKEYS_B  2502656   // 9216 u64       = 73,728
#define SBOX_B   2576384   // 9216 float4    = 147,456
#define KEPT_B   2723840   // 144 u64        = 1,152
#define MASK_B   2725888   // 9216*144 u64   = 10,616,832  (end 13,342,720)
#define WS_NEED  13400000

// ================= conv 3x3 (256->512, 32x32, pad 1) + ReLU =================
// 512 blocks = (channel-pair cp, image-half h). 256 threads: thread = 2px x
// 2ch (4 fp64 accs). Input tile fp32 in LDS, DOUBLE-BUFFERED (1 barrier/tile).
// Weights: scalar loads + per-cl fp64 cvt in regs (ZERO weight ds traffic).
// ds per (cl,ky) = 2x ds_read_b64 serving 12 fp64 FMA -> VALU-bound.
#define CPITCH 38
#define CCHS   (18 * CPITCH)           // 684 floats per channel slice

__global__ __launch_bounds__(256) void conv3x3_relu_k(
    const float* __restrict__ feat, const float* __restrict__ w,
    const float* __restrict__ bias, float* __restrict__ xout)
{
  __shared__ float il[2][8 * CCHS];    // 2 x 21,888 B
  const int cp = blockIdx.x >> 1, h = blockIdx.x & 1;
  const int tid = threadIdx.x;
  const int h16 = h << 4;
  const int co0 = cp << 1;
  for (int i = tid; i < 8 * CCHS; i += 256) { il[0][i] = 0.0f; il[1][i] = 0.0f; }

  const int yl = tid >> 4;             // 0..15
  const int x0 = (tid & 15) << 1;      // 0..30 even
  double aA0 = 0.0, aA1 = 0.0, aB0 = 0.0, aB1 = 0.0;

  const float4* feat4 = (const float4*)feat;
  // staging: 8ch x 18rows x 8 float4 = 1152 float4 -> 5 predicated per thread
  float4 pf[5];
  int pch[5], pt[5], pc4[5], pok[5];
  #pragma unroll
  for (int k = 0; k < 5; ++k) {
    const int i = tid + (k << 8);
    const int ch = i / 144, rem = i - ch * 144;
    const int t = rem >> 3, c4 = rem & 7;
    const int g = h16 - 1 + t;
    pch[k] = ch; pt[k] = t; pc4[k] = c4;
    pok[k] = (i < 1152) && ((unsigned)g < 32u);
    pf[k] = pok[k] ? feat4[(ch << 8) + (g << 3) + c4] : float4{0.f,0.f,0.f,0.f};
  }
  __syncthreads();                     // zero-init visible

  for (int cc = 0; cc < 256; cc += 8) {
    const int buf = (cc >> 3) & 1;
    // write tile regs -> LDS buf
    #pragma unroll
    for (int k = 0; k < 5; ++k) {
      if (pok[k]) {
        float* p = &il[buf][pch[k] * CCHS + pt[k] * CPITCH + (pc4[k] << 2) + 1];
        p[0] = pf[k].x; p[1] = pf[k].y; p[2] = pf[k].z; p[3] = pf[k].w;
      }
    }
    // issue next tile's global loads (overlap with compute below)
    if (cc + 8 < 256) {
      #pragma unroll
      for (int k = 0; k < 5; ++k) {
        const int g = h16 - 1 + pt[k];
        if (pok[k]) pf[k] = feat4[((cc + 8 + pch[k]) << 8) + (g << 3) + pc4[k]];
      }
    }
    __syncthreads();                   // tile ready (single barrier per tile)
    #pragma unroll
    for (int cl = 0; cl < 8; ++cl) {
      const int ci = cc + cl;
      const float* wAp = w + co0 * 2304 + ci * 9;    // uniform -> s_load
      const float* wBp = wAp + 2304;
      double wa[9], wb[9];
      #pragma unroll
      for (int q = 0; q < 9; ++q) { wa[q] = (double)wAp[q]; wb[q] = (double)wBp[q]; }
      const float* ir = &il[buf][cl * CCHS + yl * CPITCH + x0];
      #pragma unroll
      for (int ky = 0; ky < 3; ++ky) {
        const float2 q0 = *(const float2*)(ir + ky * CPITCH);
        const float2 q1 = *(const float2*)(ir + ky * CPITCH + 2);
        const double v0 = (double)q0.x, v1 = (double)q0.y;
        const double v2 = (double)q1.x, v3 = (double)q1.y;
        aA0 += v0 * wa[3*ky+0] + v1 * wa[3*ky+1] + v2 * wa[3*ky+2];
        aA1 += v1 * wa[3*ky+0] + v2 * wa[3*ky+1] + v3 * wa[3*ky+2];
        aB0 += v0 * wb[3*ky+0] + v1 * wb[3*ky+1] + v2 * wb[3*ky+2];
        aB1 += v1 * wb[3*ky+0] + v2 * wb[3*ky+1] + v3 * wb[3*ky+2];
      }
    }
  }
  const double bA = (double)bias[co0], bB = (double)bias[co0 + 1];
  const int y = h16 + yl;
  float2 rA, rB;
  rA.x = (float)fmax(aA0 + bA, 0.0); rA.y = (float)fmax(aA1 + bA, 0.0);
  rB.x = (float)fmax(aB0 + bB, 0.0); rB.y = (float)fmax(aB1 + bB, 0.0);
  *(float2*)&xout[(co0 << 10) + (y << 5) + x0] = rA;
  *(float2*)&xout[((co0 + 1) << 10) + (y << 5) + x0] = rB;
}

// ================= 1x1 heads: cls (18ch -> sigmoid -> out) + bbox (36ch) ====
__global__ __launch_bounds__(256) void head1x1_k(
    const float* __restrict__ x,
    const float* __restrict__ cls_w, const float* __restrict__ cls_b,
    const float* __restrict__ bbox_w, const float* __restrict__ bbox_b,
    float* __restrict__ out, float* __restrict__ bbox_out)
{
  __shared__ float wl[512];
  const int bid = blockIdx.x;
  const int co = bid >> 2;
  const int px = ((bid & 3) << 8) | threadIdx.x;
  const bool is_cls = co < 18;
  const float* wsrc = is_cls ? (cls_w + co * 512) : (bbox_w + (co - 18) * 512);
  for (int i = threadIdx.x; i < 512; i += 256) wl[i] = wsrc[i];
  __syncthreads();
  double acc0 = 0.0, acc1 = 0.0, acc2 = 0.0, acc3 = 0.0;
  #pragma unroll 4
  for (int c = 0; c < 512; c += 4) {
    acc0 += (double)x[((c + 0) << 10) | px] * (double)wl[c + 0];
    acc1 += (double)x[((c + 1) << 10) | px] * (double)wl[c + 1];
    acc2 += (double)x[((c + 2) << 10) | px] * (double)wl[c + 2];
    acc3 += (double)x[((c + 3) << 10) | px] * (double)wl[c + 3];
  }
  double acc = ((acc0 + acc1) + (acc2 + acc3)) +
               (double)(is_cls ? cls_b[co] : bbox_b[co - 18]);
  if (is_cls)
    out[36864 + (co << 10) + px] = (float)(1.0 / (1.0 + exp(-acc)));
  else
    bbox_out[((co - 18) << 10) + px] = (float)acc;
}

// ============ anchors + box decode + clip + key build + rank zero ===========
__global__ __launch_bounds__(256) void proposals_k(
    const float* __restrict__ bbox, const int* __restrict__ imgsz,
    const float* __restrict__ out, float* __restrict__ props,
    unsigned long long* __restrict__ keys, unsigned* __restrict__ rank)
{
  const int r = blockIdx.x * 256 + threadIdx.x;
  if (r >= 9216) return;
  const float4 d = ((const float4*)bbox)[r];
  const int cell = r / 9, a = r - cell * 9;
  const int ix = cell & 31, iy = cell >> 5;
  const int ri = a / 3, si = a - ri * 3;
  const double ratio = (ri == 0) ? 0.5 : (ri == 1 ? 1.0 : 2.0);
  const double scale = (si == 0) ? 128.0 : (si == 1 ? 256.0 : 512.0);
  const double hr = sqrt(ratio), wr = 1.0 / hr;
  const double bx = nearbyint(wr * scale * 0.5);
  const double by = nearbyint(hr * scale * 0.5);
  const double cx = ix * 16.0, cy = iy * 16.0;
  const double w = 2.0 * bx, hh = 2.0 * by;
  const double pcx = (double)d.x * w + cx;
  const double pcy = (double)d.y * hh + cy;
  const double pw = exp((double)d.z) * w;
  const double ph = exp((double)d.w) * hh;
  const double im = (double)imgsz[0];
  float4 o;
  o.x = (float)fmin(fmax(pcx - 0.5 * pw, 0.0), im);
  o.y = (float)fmin(fmax(pcy - 0.5 * ph, 0.0), im);
  o.z = (float)fmin(fmax(pcx + 0.5 * pw, 0.0), im);
  o.w = (float)fmin(fmax(pcy + 0.5 * ph, 0.0), im);
  ((float4*)props)[r] = o;
  const float s = out[36864 + ((2 * (r >> 10) + 1) << 10) + (r & 1023)];
  keys[r] = ((unsigned long long)__float_as_uint(s) << 32) |
            (unsigned)(0x7FFFFFFF - r);
  rank[r] = 0u;
}

// ================= rank sort: rank[j] = #{i : key_i > key_j} ================
// 576 blocks = 36 j-tiles x 16 i-chunks (576 keys each, in lane regs).
__global__ __launch_bounds__(256) void rank_k(
    const unsigned long long* __restrict__ keys, unsigned* __restrict__ rank)
{
  const int jt = blockIdx.x % 36, ic = blockIdx.x / 36;
  const int j = jt * 256 + threadIdx.x;
  const unsigned long long kj = keys[j];
  const int lane = threadIdx.x & 63;
  const int base = ic * 576;
  unsigned lo[9], hi[9];
  #pragma unroll
  for (int rr = 0; rr < 9; ++rr) {
    const unsigned long long k = keys[base + rr * 64 + lane];
    lo[rr] = (unsigned)k; hi[rr] = (unsigned)(k >> 32);
  }
  unsigned cnt = 0;
  #pragma unroll
  for (int rr = 0; rr < 9; ++rr) {
    #pragma unroll
    for (int l = 0; l < 64; ++l) {
      const unsigned llo = (unsigned)__builtin_amdgcn_readlane((int)lo[rr], l);
      const unsigned lhi = (unsigned)__builtin_amdgcn_readlane((int)hi[rr], l);
      const unsigned long long ki = ((unsigned long long)lhi << 32) | llo;
      cnt += (ki > kj) ? 1u : 0u;
    }
  }
  atomicAdd(&rank[j], cnt);
}

// ================= scatter into sorted order ================================
__global__ __launch_bounds__(256) void scatter_k(
    const unsigned long long* __restrict__ keys, const unsigned* __restrict__ rank,
    const float* __restrict__ props, unsigned long long* __restrict__ skeys,
    float4* __restrict__ sboxes)
{
  const int r = blockIdx.x * 256 + threadIdx.x;
  if (r >= 9216) return;
  const unsigned rk = rank[r];
  skeys[rk] = keys[r];
  sboxes[rk] = ((const float4*)props)[r];
}

// ================= suppression bitmask: mask[i][W] over sorted boxes ========
// grid (18 i-chunks x 144 j-words), 64 threads (1 wave). Lane j = W*64+lane
// held in regs; loop i over chunk (uniform load), ballot 64 preds -> 1 word.
// Only words W >= i>>6 are written (lower words never read by sweep).
__global__ __launch_bounds__(64) void mask_k(
    const float4* __restrict__ sb4, unsigned long long* __restrict__ mask)
{
  const int c = blockIdx.x, W = blockIdx.y;
  const int i_lo = c * 512;
  const int i_hi = min(i_lo + 512, W * 64 + 64);
  if (i_lo >= i_hi) return;
  const int lane = threadIdx.x;
  const float4 bj = sb4[(W << 6) + lane];
  const float areaJ = (bj.z - bj.x) * (bj.w - bj.y);
  for (int i = i_lo; i < i_hi; ++i) {
    const float4 bi = sb4[i];                       // uniform -> s_load
    const float areaI = (bi.z - bi.x) * (bi.w - bi.y);
    const float ix1 = fmaxf(bj.x, bi.x), iy1 = fmaxf(bj.y, bi.y);
    const float ix2 = fminf(bj.z, bi.z), iy2 = fminf(bj.w, bi.w);
    const float iw = fmaxf(ix2 - ix1, 0.0f), ih = fmaxf(iy2 - iy1, 0.0f);
    const double inter = (double)iw * (double)ih;
    const double uni = (double)areaJ + (double)areaI - inter + 1e-9;
    const unsigned long long bal = __ballot(inter > 0.3 * uni);
    if (lane == 0) mask[(size_t)i * 144 + W] = bal;
  }
}

// ================= sweep: exact sequential NMS over the bitmask =============
// ONE wave. Alive bitmap 144 words in regs (lane l: words l, 64+l, 128+l).
// Pop min alive bit (== next in sorted order == next kept), AND its row.
__global__ __launch_bounds__(64) void sweep_k(
    const unsigned long long* __restrict__ mask, unsigned long long* __restrict__ keptw)
{
  const int l = threadIdx.x;
  unsigned long long a0 = ~0ULL, a1 = ~0ULL, a2 = (l < 16) ? ~0ULL : 0ULL;
  unsigned long long k0 = 0, k1 = 0, k2 = 0;
  for (int it = 0; it < 9216; ++it) {
    int pos = 0x40000000;
    if (a0)      pos = (l << 6) + (int)__builtin_ctzll(a0);
    else if (a1) pos = ((64 + l) << 6) + (int)__builtin_ctzll(a1);
    else if (a2) pos = ((128 + l) << 6) + (int)__builtin_ctzll(a2);
    #pragma unroll
    for (int off = 32; off; off >>= 1) {
      const int o = __shfl_down(pos, off, 64);
      pos = pos < o ? pos : o;
    }
    pos = __shfl(pos, 0, 64);
    if (pos >= 9216) break;
    const int w = pos >> 6, b = pos & 63;
    if (w < 64)       { if (l == w)       { a0 &= ~(1ULL << b); k0 |= 1ULL << b; } }
    else if (w < 128) { if (l == w - 64)  { a1 &= ~(1ULL << b); k1 |= 1ULL << b; } }
    else              { if (l == w - 128) { a2 &= ~(1ULL << b); k2 |= 1ULL << b; } }
    const size_t base = (size_t)pos * 144;
    const unsigned long long r0 = mask[base + l];
    const unsigned long long r1 = mask[base + 64 + l];
    const unsigned long long r2 = (l < 16) ? mask[base + 128 + l] : 0ULL;
    // words < pos>>6 may be garbage, but their alive bits are already 0.
    a0 &= ~r0; a1 &= ~r1; a2 &= ~r2;
  }
  keptw[l] = k0; keptw[64 + l] = k1; if (l < 16) keptw[128 + l] = k2;
}

// ================= output scatter ===========================================
__global__ __launch_bounds__(256) void outk(
    const unsigned long long* __restrict__ skeys, const float4* __restrict__ sboxes,
    const unsigned long long* __restrict__ keptw, float* __restrict__ out)
{
  const int r = blockIdx.x * 256 + threadIdx.x;
  if (r >= 9216) return;
  const unsigned long long key = skeys[r];
  const int orig = 0x7FFFFFFF - (int)(unsigned)(key & 0xFFFFFFFFULL);
  const bool kp = (keptw[r >> 6] >> (r & 63)) & 1ULL;
  float4 ob = sboxes[r];
  if (!kp) { ob.x = 0.f; ob.y = 0.f; ob.z = 0.f; ob.w = 0.f; }
  ((float4*)out)[orig] = ob;
  out[55296 + orig] = kp ? 1.0f : 0.0f;
}

// ================= fallback NMS (small ws) — R2's known-good 231 us =========
__global__ __launch_bounds__(1024) void nms_fallback_k(
    const float* __restrict__ props, float* __restrict__ out)
{
  __shared__ unsigned long long wmax[16];
  __shared__ float4 curBoxS;
  const int tid = threadIdx.x, wid = tid >> 6, lane = tid & 63;
  unsigned long long key[9];
  float4 box[9];
  #pragma unroll
  for (int j = 0; j < 9; ++j) {
    const int r = tid + (j << 10);
    box[j] = ((const float4*)props)[r];
    const float s = out[36864 + ((2 * (r >> 10) + 1) << 10) + (r & 1023)];
    key[j] = ((unsigned long long)__float_as_uint(s) << 32) |
             (unsigned)(0x7FFFFFFF - r);
  }
  unsigned kept = 0;
  for (;;) {
    unsigned long long m = key[0];
    #pragma unroll
    for (int j = 1; j < 9; ++j) m = key[j] > m ? key[j] : m;
    #pragma unroll
    for (int off = 32; off; off >>= 1) {
      const unsigned long long o = __shfl_down(m, off, 64);
      if (o > m) m = o;
    }
    if (lane == 0) wmax[wid] = m;
    __syncthreads();
    unsigned long long K = wmax[0];
    #pragma unroll
    for (int wv = 1; wv < 16; ++wv) { const unsigned long long t = wmax[wv]; if (t > K) K = t; }
    if (K == 0) break;
    #pragma unroll
    for (int j = 0; j < 9; ++j)
      if (key[j] == K) { curBoxS = box[j]; key[j] = 0; kept |= 1u << j; }
    __syncthreads();
    const float4 cb = curBoxS;
    const float areaC = (cb.z - cb.x) * (cb.w - cb.y);
    #pragma unroll
    for (int j = 0; j < 9; ++j) {
      if (key[j]) {
        const float4 b = box[j];
        const float ix1 = fmaxf(b.x, cb.x), iy1 = fmaxf(b.y, cb.y);
        const float ix2 = fminf(b.z, cb.z), iy2 = fminf(b.w, cb.w);
        const float iw = fmaxf(ix2 - ix1, 0.0f), ih = fmaxf(iy2 - iy1, 0.0f);
        const float areaB = (b.z - b.x) * (b.w - b.y);
        const double inter = (double)iw * (double)ih;
        const double uni = (double)areaB + (double)areaC - inter + 1e-9;
        if (inter > 0.3 * uni) key[j] = 0;
      }
    }
    __syncthreads();
  }
  #pragma unroll
  for (int j = 0; j < 9; ++j) {
    const int r = tid + (j << 10);
    const bool kp = (kept >> j) & 1u;
    float4 ob = box[j];
    if (!kp) { ob.x = 0.f; ob.y = 0.f; ob.z = 0.f; ob.w = 0.f; }
    ((float4*)out)[r] = ob;
    out[55296 + r] = kp ? 1.0f : 0.0f;
  }
}

// ============================================================================
extern "C" void kernel_launch(void* const* d_in, const int* in_sizes, int n_in,
                              void* d_out, int out_size, void* d_ws, size_t ws_size,
                              hipStream_t stream)
{
  const float* feat   = (const float*)d_in[0];
  const int*   imgsz  = (const int*)d_in[1];
  const float* conv_w = (const float*)d_in[2];
  const float* conv_b = (const float*)d_in[3];
  const float* cls_w  = (const float*)d_in[4];
  const float* cls_b  = (const float*)d_in[5];
  const float* bbox_w = (const float*)d_in[6];
  const float* bbox_b = (const float*)d_in[7];
  float* out = (float*)d_out;
  char*  ws  = (char*)d_ws;
  float* x      = (float*)(ws + X_B);
  float* bbox   = (float*)(ws + BBOX_B);
  float* props  = (float*)(ws + PROPS_B);
  unsigned long long* keys  = (unsigned long long*)(ws + KEYS_B);
  unsigned*           rankp = (unsigned*)(ws + RANK_B);
  unsigned long long* skeys = (unsigned long long*)(ws + SKEYS_B);
  float4*             sboxs = (float4*)(ws + SBOX_B);
  unsigned long long* keptw = (unsigned long long*)(ws + KEPT_B);
  unsigned long long* maskp = (unsigned long long*)(ws + MASK_B);

  hipLaunchKernelGGL(conv3x3_relu_k, dim3(512), dim3(256), 0, stream,
                     feat, conv_w, conv_b, x);
  hipLaunchKernelGGL(head1x1_k, dim3(216), dim3(256), 0, stream,
                     x, cls_w, cls_b, bbox_w, bbox_b, out, bbox);
  hipLaunchKernelGGL(proposals_k, dim3(36), dim3(256), 0, stream,
                     bbox, imgsz, out, props, keys, rankp);
  if (ws_size >= (size_t)WS_NEED) {
    hipLaunchKernelGGL(rank_k, dim3(576), dim3(256), 0, stream, keys, rankp);
    hipLaunchKernelGGL(scatter_k, dim3(36), dim3(256), 0, stream,
                       keys, rankp, props, skeys, sboxs);
    hipLaunchKernelGGL(mask_k, dim3(18, 144), dim3(64), 0, stream, sboxs, maskp);
    hipLaunchKernelGGL(sweep_k, dim3(1), dim3(64), 0, stream, maskp, keptw);
    hipLaunchKernelGGL(outk, dim3(36), dim3(256), 0, stream,
                       skeys, sboxs, keptw, out);
  } else {
    hipLaunchKernelGGL(nms_fallback_k, dim3(1), dim3(1024), 0, stream,
                       props, out);
  }
}

// Round 5
// 385.615 us; speedup vs baseline: 1.3282x; 1.0257x over previous
//
#include <hip/hip_runtime.h>
#include <math.h>

// ---------------- workspace layout (bytes) ----------------
#define X_B      0         // 512*1024 f32   = 2,097,152
#define BBOX_B   2097152   // 36*1024 f32    = 147,456
#define PROPS_B  2244608   // 9216 float4    = 147,456
#define KEYS_B   2392064   // 9216 u64       = 73,728
#define RANK_B   2465792   // 9216 u32       = 36,864
#define SKEYS_B  2502656   // 9216 u64       = 73,728
#define SBOX_B   2576384   // 9216 float4    = 147,456
#define KEPT_B   2723840   // 144 u64        = 1,152
#define MASK_B   2725888   // 9216*144 u64   = 10,616,832 (end 13,342,720)
// fp64 weights (512*2304*8 = 9,437,184 B) OVERLAP the mask region: conv
// consumes wd before mask_k overwrites it (same stream, serialized).
#define WD_B     MASK_B
#define WS_NEED  13400000

// ================= prep: convert conv weights to fp64 =======================
__global__ __launch_bounds__(256) void prep_wd_k(
    const float* __restrict__ w, double* __restrict__ wd)
{
  const int i = blockIdx.x * 256 + threadIdx.x;
  if (i < 512 * 2304) wd[i] = (double)w[i];
}

// ================= conv 3x3 (256->512, 32x32, pad 1) + ReLU =================
// 512 blocks = (channel-pair cp, image-half himg), 512 threads = 2 K-halves
// (waves 0-3: ci 0..127, waves 4-7: ci 128..255) x 256 px-threads (2px x 2ch,
// 4 fp64 accs). fp64 weights via wave-uniform scalar loads (zero VALU cvt,
// zero ds). Input fp32 tile (4ch x 18rows x pitch38) double-buffered, zero
// halo. Cross-half reduce through LDS at the end. 16 waves/CU.
#define CPITCH 38
#define CCHS   (18 * CPITCH)   // 684 floats per channel slice

__global__ __launch_bounds__(512) void conv3x3_relu_k(
    const float* __restrict__ feat, const double* __restrict__ wd,
    const float* __restrict__ bias, float* __restrict__ xout)
{
  __shared__ float il[2][2][4 * CCHS];   // [khalf][buf][...] = 43,776 B
  const int cp = blockIdx.x >> 1, himg = blockIdx.x & 1;
  const int tid = threadIdx.x;
  const int kh = __builtin_amdgcn_readfirstlane(tid >> 8);  // wave-uniform 0/1
  const int t  = tid & 255;
  const int h16 = himg << 4;
  const int co0 = cp << 1;
  for (int i = tid; i < 2 * 2 * 4 * CCHS; i += 512) ((float*)il)[i] = 0.0f;

  const int yl = t >> 4;               // 0..15
  const int x0 = (t & 15) << 1;        // 0..30 even
  double aA0 = 0.0, aA1 = 0.0, aB0 = 0.0, aB1 = 0.0;

  const float4* feat4 = (const float4*)feat;
  // staging: 4ch x 18rows x 8 float4 = 576 float4 over 256 threads -> 3 slots
  float4 pf[3]; int pch[3], pt[3], pc4[3], pok[3];
  #pragma unroll
  for (int k = 0; k < 3; ++k) {
    const int i = t + (k << 8);
    const int ch = i / 144, rem = i - ch * 144;
    const int row = rem >> 3, c4 = rem & 7;
    const int g = h16 - 1 + row;
    pch[k] = ch; pt[k] = row; pc4[k] = c4;
    pok[k] = (i < 576) && ((unsigned)g < 32u);
    pf[k] = pok[k] ? feat4[((kh * 128 + ch) << 8) + (g << 3) + c4]
                   : float4{0.f, 0.f, 0.f, 0.f};
  }
  __syncthreads();                     // zero-init visible before stores

  for (int cc = 0; cc < 128; cc += 4) {
    const int buf = (cc >> 2) & 1;
    #pragma unroll
    for (int k = 0; k < 3; ++k)
      if (pok[k]) {
        float* p = &il[kh][buf][pch[k] * CCHS + pt[k] * CPITCH + (pc4[k] << 2) + 1];
        p[0] = pf[k].x; p[1] = pf[k].y; p[2] = pf[k].z; p[3] = pf[k].w;
      }
    if (cc + 4 < 128) {
      #pragma unroll
      for (int k = 0; k < 3; ++k) {
        const int g = h16 - 1 + pt[k];
        if (pok[k]) pf[k] = feat4[((kh * 128 + cc + 4 + pch[k]) << 8) + (g << 3) + pc4[k]];
      }
    }
    __syncthreads();   // single barrier per tile (double-buffered)
    #pragma unroll
    for (int cl = 0; cl < 4; ++cl) {
      const double* wA = wd + (size_t)co0 * 2304 + (size_t)(kh * 128 + cc + cl) * 9;
      const double* wB = wA + 2304;
      const float* ir = &il[kh][buf][cl * CCHS + yl * CPITCH + x0];
      #pragma unroll
      for (int ky = 0; ky < 3; ++ky) {
        const float2 q0 = *(const float2*)(ir + ky * CPITCH);
        const float2 q1 = *(const float2*)(ir + ky * CPITCH + 2);
        const double v0 = (double)q0.x, v1 = (double)q0.y;
        const double v2 = (double)q1.x, v3 = (double)q1.y;
        const double w0 = wA[3*ky+0], w1 = wA[3*ky+1], w2 = wA[3*ky+2];
        const double u0 = wB[3*ky+0], u1 = wB[3*ky+1], u2 = wB[3*ky+2];
        aA0 += v0 * w0 + v1 * w1 + v2 * w2;
        aA1 += v1 * w0 + v2 * w1 + v3 * w2;
        aB0 += v0 * u0 + v1 * u1 + v2 * u2;
        aB1 += v1 * u0 + v2 * u1 + v3 * u2;
      }
    }
  }
  // cross-half reduce: red reuses il[0][*] (disjoint from il[1][*])
  double* red = (double*)&il[0][0][0];           // 8 KB
  if (kh == 0) {
    red[t * 4 + 0] = aA0; red[t * 4 + 1] = aA1;
    red[t * 4 + 2] = aB0; red[t * 4 + 3] = aB1;
  }
  __syncthreads();
  if (kh == 1) {
    const double bA = (double)bias[co0], bB = (double)bias[co0 + 1];
    const int y = h16 + yl;
    float2 rA, rB;
    rA.x = (float)fmax(red[t*4+0] + aA0 + bA, 0.0);
    rA.y = (float)fmax(red[t*4+1] + aA1 + bA, 0.0);
    rB.x = (float)fmax(red[t*4+2] + aB0 + bB, 0.0);
    rB.y = (float)fmax(red[t*4+3] + aB1 + bB, 0.0);
    *(float2*)&xout[(co0 << 10) + (y << 5) + x0] = rA;
    *(float2*)&xout[((co0 + 1) << 10) + (y << 5) + x0] = rB;
  }
}

// ========== fallback conv (small ws: no wd buffer) — R4's version ===========
__global__ __launch_bounds__(256) void conv3x3_relu_fb_k(
    const float* __restrict__ feat, const float* __restrict__ w,
    const float* __restrict__ bias, float* __restrict__ xout)
{
  __shared__ float il[2][8 * CCHS];
  const int cp = blockIdx.x >> 1, h = blockIdx.x & 1;
  const int tid = threadIdx.x;
  const int h16 = h << 4;
  const int co0 = cp << 1;
  for (int i = tid; i < 8 * CCHS; i += 256) { il[0][i] = 0.0f; il[1][i] = 0.0f; }
  const int yl = tid >> 4;
  const int x0 = (tid & 15) << 1;
  double aA0 = 0.0, aA1 = 0.0, aB0 = 0.0, aB1 = 0.0;
  const float4* feat4 = (const float4*)feat;
  float4 pf[5]; int pch[5], pt[5], pc4[5], pok[5];
  #pragma unroll
  for (int k = 0; k < 5; ++k) {
    const int i = tid + (k << 8);
    const int ch = i / 144, rem = i - ch * 144;
    const int t = rem >> 3, c4 = rem & 7;
    const int g = h16 - 1 + t;
    pch[k] = ch; pt[k] = t; pc4[k] = c4;
    pok[k] = (i < 1152) && ((unsigned)g < 32u);
    pf[k] = pok[k] ? feat4[(ch << 8) + (g << 3) + c4] : float4{0.f,0.f,0.f,0.f};
  }
  __syncthreads();
  for (int cc = 0; cc < 256; cc += 8) {
    const int buf = (cc >> 3) & 1;
    #pragma unroll
    for (int k = 0; k < 5; ++k)
      if (pok[k]) {
        float* p = &il[buf][pch[k] * CCHS + pt[k] * CPITCH + (pc4[k] << 2) + 1];
        p[0] = pf[k].x; p[1] = pf[k].y; p[2] = pf[k].z; p[3] = pf[k].w;
      }
    if (cc + 8 < 256) {
      #pragma unroll
      for (int k = 0; k < 5; ++k) {
        const int g = h16 - 1 + pt[k];
        if (pok[k]) pf[k] = feat4[((cc + 8 + pch[k]) << 8) + (g << 3) + pc4[k]];
      }
    }
    __syncthreads();
    #pragma unroll
    for (int cl = 0; cl < 8; ++cl) {
      const float* wAp = w + co0 * 2304 + (cc + cl) * 9;
      const float* wBp = wAp + 2304;
      double wa[9], wb[9];
      #pragma unroll
      for (int q = 0; q < 9; ++q) { wa[q] = (double)wAp[q]; wb[q] = (double)wBp[q]; }
      const float* ir = &il[buf][cl * CCHS + yl * CPITCH + x0];
      #pragma unroll
      for (int ky = 0; ky < 3; ++ky) {
        const float2 q0 = *(const float2*)(ir + ky * CPITCH);
        const float2 q1 = *(const float2*)(ir + ky * CPITCH + 2);
        const double v0 = (double)q0.x, v1 = (double)q0.y;
        const double v2 = (double)q1.x, v3 = (double)q1.y;
        aA0 += v0 * wa[3*ky+0] + v1 * wa[3*ky+1] + v2 * wa[3*ky+2];
        aA1 += v1 * wa[3*ky+0] + v2 * wa[3*ky+1] + v3 * wa[3*ky+2];
        aB0 += v0 * wb[3*ky+0] + v1 * wb[3*ky+1] + v2 * wb[3*ky+2];
        aB1 += v1 * wb[3*ky+0] + v2 * wb[3*ky+1] + v3 * wb[3*ky+2];
      }
    }
  }
  const double bA = (double)bias[co0], bB = (double)bias[co0 + 1];
  const int y = h16 + yl;
  float2 rA, rB;
  rA.x = (float)fmax(aA0 + bA, 0.0); rA.y = (float)fmax(aA1 + bA, 0.0);
  rB.x = (float)fmax(aB0 + bB, 0.0); rB.y = (float)fmax(aB1 + bB, 0.0);
  *(float2*)&xout[(co0 << 10) + (y << 5) + x0] = rA;
  *(float2*)&xout[((co0 + 1) << 10) + (y << 5) + x0] = rB;
}

// ================= 1x1 heads: cls (18ch -> sigmoid -> out) + bbox (36ch) ====
__global__ __launch_bounds__(256) void head1x1_k(
    const float* __restrict__ x,
    const float* __restrict__ cls_w, const float* __restrict__ cls_b,
    const float* __restrict__ bbox_w, const float* __restrict__ bbox_b,
    float* __restrict__ out, float* __restrict__ bbox_out)
{
  __shared__ float wl[512];
  const int bid = blockIdx.x;
  const int co = bid >> 2;
  const int px = ((bid & 3) << 8) | threadIdx.x;
  const bool is_cls = co < 18;
  const float* wsrc = is_cls ? (cls_w + co * 512) : (bbox_w + (co - 18) * 512);
  for (int i = threadIdx.x; i < 512; i += 256) wl[i] = wsrc[i];
  __syncthreads();
  double acc0 = 0.0, acc1 = 0.0, acc2 = 0.0, acc3 = 0.0;
  #pragma unroll 4
  for (int c = 0; c < 512; c += 4) {
    acc0 += (double)x[((c + 0) << 10) | px] * (double)wl[c + 0];
    acc1 += (double)x[((c + 1) << 10) | px] * (double)wl[c + 1];
    acc2 += (double)x[((c + 2) << 10) | px] * (double)wl[c + 2];
    acc3 += (double)x[((c + 3) << 10) | px] * (double)wl[c + 3];
  }
  double acc = ((acc0 + acc1) + (acc2 + acc3)) +
               (double)(is_cls ? cls_b[co] : bbox_b[co - 18]);
  if (is_cls)
    out[36864 + (co << 10) + px] = (float)(1.0 / (1.0 + exp(-acc)));
  else
    bbox_out[((co - 18) << 10) + px] = (float)acc;
}

// ============ anchors + box decode + clip + key build + rank zero ===========
__global__ __launch_bounds__(256) void proposals_k(
    const float* __restrict__ bbox, const int* __restrict__ imgsz,
    const float* __restrict__ out, float* __restrict__ props,
    unsigned long long* __restrict__ keys, unsigned* __restrict__ rank)
{
  const int r = blockIdx.x * 256 + threadIdx.x;
  if (r >= 9216) return;
  const float4 d = ((const float4*)bbox)[r];
  const int cell = r / 9, a = r - cell * 9;
  const int ix = cell & 31, iy = cell >> 5;
  const int ri = a / 3, si = a - ri * 3;
  const double ratio = (ri == 0) ? 0.5 : (ri == 1 ? 1.0 : 2.0);
  const double scale = (si == 0) ? 128.0 : (si == 1 ? 256.0 : 512.0);
  const double hr = sqrt(ratio), wr = 1.0 / hr;
  const double bx = nearbyint(wr * scale * 0.5);
  const double by = nearbyint(hr * scale * 0.5);
  const double cx = ix * 16.0, cy = iy * 16.0;
  const double w = 2.0 * bx, hh = 2.0 * by;
  const double pcx = (double)d.x * w + cx;
  const double pcy = (double)d.y * hh + cy;
  const double pw = exp((double)d.z) * w;
  const double ph = exp((double)d.w) * hh;
  const double im = (double)imgsz[0];
  float4 o;
  o.x = (float)fmin(fmax(pcx - 0.5 * pw, 0.0), im);
  o.y = (float)fmin(fmax(pcy - 0.5 * ph, 0.0), im);
  o.z = (float)fmin(fmax(pcx + 0.5 * pw, 0.0), im);
  o.w = (float)fmin(fmax(pcy + 0.5 * ph, 0.0), im);
  ((float4*)props)[r] = o;
  const float s = out[36864 + ((2 * (r >> 10) + 1) << 10) + (r & 1023)];
  keys[r] = ((unsigned long long)__float_as_uint(s) << 32) |
            (unsigned)(0x7FFFFFFF - r);
  rank[r] = 0u;
}

// ================= rank sort: rank[j] = #{i : key_i > key_j} ================
__global__ __launch_bounds__(256) void rank_k(
    const unsigned long long* __restrict__ keys, unsigned* __restrict__ rank)
{
  const int jt = blockIdx.x % 36, ic = blockIdx.x / 36;
  const int j = jt * 256 + threadIdx.x;
  const unsigned long long kj = keys[j];
  const int lane = threadIdx.x & 63;
  const int base = ic * 576;
  unsigned lo[9], hi[9];
  #pragma unroll
  for (int rr = 0; rr < 9; ++rr) {
    const unsigned long long k = keys[base + rr * 64 + lane];
    lo[rr] = (unsigned)k; hi[rr] = (unsigned)(k >> 32);
  }
  unsigned cnt = 0;
  #pragma unroll
  for (int rr = 0; rr < 9; ++rr) {
    #pragma unroll
    for (int l = 0; l < 64; ++l) {
      const unsigned llo = (unsigned)__builtin_amdgcn_readlane((int)lo[rr], l);
      const unsigned lhi = (unsigned)__builtin_amdgcn_readlane((int)hi[rr], l);
      const unsigned long long ki = ((unsigned long long)lhi << 32) | llo;
      cnt += (ki > kj) ? 1u : 0u;
    }
  }
  atomicAdd(&rank[j], cnt);
}

// ================= scatter into sorted order ================================
__global__ __launch_bounds__(256) void scatter_k(
    const unsigned long long* __restrict__ keys, const unsigned* __restrict__ rank,
    const float* __restrict__ props, unsigned long long* __restrict__ skeys,
    float4* __restrict__ sboxes)
{
  const int r = blockIdx.x * 256 + threadIdx.x;
  if (r >= 9216) return;
  const unsigned rk = rank[r];
  skeys[rk] = keys[r];
  sboxes[rk] = ((const float4*)props)[r];
}

// ================= suppression bitmask over sorted boxes ====================
__global__ __launch_bounds__(64) void mask_k(
    const float4* __restrict__ sb4, unsigned long long* __restrict__ mask)
{
  const int c = blockIdx.x, W = blockIdx.y;
  const int i_lo = c * 512;
  const int i_hi = min(i_lo + 512, W * 64 + 64);
  if (i_lo >= i_hi) return;
  const int lane = threadIdx.x;
  const float4 bj = sb4[(W << 6) + lane];
  const float areaJ = (bj.z - bj.x) * (bj.w - bj.y);
  for (int i = i_lo; i < i_hi; ++i) {
    const float4 bi = sb4[i];
    const float areaI = (bi.z - bi.x) * (bi.w - bi.y);
    const float ix1 = fmaxf(bj.x, bi.x), iy1 = fmaxf(bj.y, bi.y);
    const float ix2 = fminf(bj.z, bi.z), iy2 = fminf(bj.w, bi.w);
    const float iw = fmaxf(ix2 - ix1, 0.0f), ih = fmaxf(iy2 - iy1, 0.0f);
    const double inter = (double)iw * (double)ih;
    const double uni = (double)areaJ + (double)areaI - inter + 1e-9;
    const unsigned long long bal = __ballot(inter > 0.3 * uni);
    if (lane == 0) mask[(size_t)i * 144 + W] = bal;
  }
}

// ================= sweep: batch-16 exact sequential NMS =====================
// ONE wave. Alive bitmap in regs (lane l: words l, 64+l, 128+l). Per round:
// candidates = up-to-16 lowest bits of the FIRST nonzero alive word (all
// positions < that word are dead -> pop order == sorted order). Fetch all
// candidate rows concurrently (one latency), resolve in-registers via an
// accumulated suppression word, AND kept rows into alive. Exact sequential
// semantics: kept j suppresses later candidates via sup-word / row-AND.
__global__ __launch_bounds__(64) void sweep_k(
    const unsigned long long* __restrict__ mask, unsigned long long* __restrict__ keptw)
{
  const int l = threadIdx.x;
  unsigned long long a0 = ~0ULL, a1 = ~0ULL, a2 = (l < 16) ? ~0ULL : 0ULL;
  unsigned long long k0 = 0, k1 = 0, k2 = 0;
  for (int round = 0; round < 9216; ++round) {
    const unsigned long long f0 = __ballot(a0 != 0ULL);
    const unsigned long long f1 = __ballot(a1 != 0ULL);
    const unsigned long long f2 = __ballot(a2 != 0ULL);
    int w0; unsigned long long wv;
    if (f0)      { w0 = (int)__builtin_ctzll(f0);       wv = __shfl(a0, w0, 64); }
    else if (f1) { w0 = 64 + (int)__builtin_ctzll(f1);  wv = __shfl(a1, w0 - 64, 64); }
    else if (f2) { w0 = 128 + (int)__builtin_ctzll(f2); wv = __shfl(a2, w0 - 128, 64); }
    else break;
    // keep the lowest <=16 set bits of wv
    unsigned long long c = wv;
    #pragma unroll
    for (int tt = 0; tt < 16; ++tt) c &= (c - 1ULL);
    const unsigned long long cand = wv & ~c;
    const int ncand = (int)__popcll(cand);
    int bp[16];
    unsigned long long tmp = cand;
    #pragma unroll
    for (int s = 0; s < 16; ++s) {
      bp[s] = tmp ? (int)__builtin_ctzll(tmp) : 0;
      tmp &= tmp ? (tmp - 1ULL) : 0ULL;
    }
    // fetch all candidate rows (concurrent, one latency)
    unsigned long long r0[16], r1[16], r2[16];
    #pragma unroll
    for (int s = 0; s < 16; ++s) {
      const size_t base = ((size_t)(w0 << 6) + (size_t)bp[s]) * 144;
      r0[s] = mask[base + l];
      r1[s] = mask[base + 64 + l];
      r2[s] = (l < 16) ? mask[base + 128 + l] : 0ULL;
    }
    // resolve sequentially in-registers (uniform control flow)
    const int reg = w0 >> 6, off = w0 & 63;
    unsigned long long sup = 0ULL, keptbits = 0ULL;
    #pragma unroll
    for (int s = 0; s < 16; ++s) {
      if (s < ncand) {
        if (!((sup >> bp[s]) & 1ULL)) {
          keptbits |= 1ULL << bp[s];
          unsigned long long v;
          if (reg == 0)      v = __shfl(r0[s], off, 64);
          else if (reg == 1) v = __shfl(r1[s], off, 64);
          else               v = __shfl(r2[s], off, 64);
          sup |= v;                       // this kept box's word-w0 suppressions
          a0 &= ~r0[s]; a1 &= ~r1[s]; a2 &= ~r2[s];   // full-row suppress
        }
      }
    }
    // suppressed candidates were cleared by their suppressor's row-AND;
    // kept candidates cleared themselves (self-IoU bit). Record kept.
    if (l == off) {
      if (reg == 0)      k0 |= keptbits;
      else if (reg == 1) k1 |= keptbits;
      else               k2 |= keptbits;
    }
  }
  keptw[l] = k0; keptw[64 + l] = k1; if (l < 16) keptw[128 + l] = k2;
}

// ================= output scatter ===========================================
__global__ __launch_bounds__(256) void outk(
    const unsigned long long* __restrict__ skeys, const float4* __restrict__ sboxes,
    const unsigned long long* __restrict__ keptw, float* __restrict__ out)
{
  const int r = blockIdx.x * 256 + threadIdx.x;
  if (r >= 9216) return;
  const unsigned long long key = skeys[r];
  const int orig = 0x7FFFFFFF - (int)(unsigned)(key & 0xFFFFFFFFULL);
  const bool kp = (keptw[r >> 6] >> (r & 63)) & 1ULL;
  float4 ob = sboxes[r];
  if (!kp) { ob.x = 0.f; ob.y = 0.f; ob.z = 0.f; ob.w = 0.f; }
  ((float4*)out)[orig] = ob;
  out[55296 + orig] = kp ? 1.0f : 0.0f;
}

// ================= fallback NMS (small ws) ==================================
__global__ __launch_bounds__(1024) void nms_fallback_k(
    const float* __restrict__ props, float* __restrict__ out)
{
  __shared__ unsigned long long wmax[16];
  __shared__ float4 curBoxS;
  const int tid = threadIdx.x, wid = tid >> 6, lane = tid & 63;
  unsigned long long key[9];
  float4 box[9];
  #pragma unroll
  for (int j = 0; j < 9; ++j) {
    const int r = tid + (j << 10);
    box[j] = ((const float4*)props)[r];
    const float s = out[36864 + ((2 * (r >> 10) + 1) << 10) + (r & 1023)];
    key[j] = ((unsigned long long)__float_as_uint(s) << 32) |
             (unsigned)(0x7FFFFFFF - r);
  }
  unsigned kept = 0;
  for (;;) {
    unsigned long long m = key[0];
    #pragma unroll
    for (int j = 1; j < 9; ++j) m = key[j] > m ? key[j] : m;
    #pragma unroll
    for (int off = 32; off; off >>= 1) {
      const unsigned long long o = __shfl_down(m, off, 64);
      if (o > m) m = o;
    }
    if (lane == 0) wmax[wid] = m;
    __syncthreads();
    unsigned long long K = wmax[0];
    #pragma unroll
    for (int wv = 1; wv < 16; ++wv) { const unsigned long long t = wmax[wv]; if (t > K) K = t; }
    if (K == 0) break;
    #pragma unroll
    for (int j = 0; j < 9; ++j)
      if (key[j] == K) { curBoxS = box[j]; key[j] = 0; kept |= 1u << j; }
    __syncthreads();
    const float4 cb = curBoxS;
    const float areaC = (cb.z - cb.x) * (cb.w - cb.y);
    #pragma unroll
    for (int j = 0; j < 9; ++j) {
      if (key[j]) {
        const float4 b = box[j];
        const float ix1 = fmaxf(b.x, cb.x), iy1 = fmaxf(b.y, cb.y);
        const float ix2 = fminf(b.z, cb.z), iy2 = fminf(b.w, cb.w);
        const float iw = fmaxf(ix2 - ix1, 0.0f), ih = fmaxf(iy2 - iy1, 0.0f);
        const float areaB = (b.z - b.x) * (b.w - b.y);
        const double inter = (double)iw * (double)ih;
        const double uni = (double)areaB + (double)areaC - inter + 1e-9;
        if (inter > 0.3 * uni) key[j] = 0;
      }
    }
    __syncthreads();
  }
  #pragma unroll
  for (int j = 0; j < 9; ++j) {
    const int r = tid + (j << 10);
    const bool kp = (kept >> j) & 1u;
    float4 ob = box[j];
    if (!kp) { ob.x = 0.f; ob.y = 0.f; ob.z = 0.f; ob.w = 0.f; }
    ((float4*)out)[r] = ob;
    out[55296 + r] = kp ? 1.0f : 0.0f;
  }
}

// ============================================================================
extern "C" void kernel_launch(void* const* d_in, const int* in_sizes, int n_in,
                              void* d_out, int out_size, void* d_ws, size_t ws_size,
                              hipStream_t stream)
{
  const float* feat   = (const float*)d_in[0];
  const int*   imgsz  = (const int*)d_in[1];
  const float* conv_w = (const float*)d_in[2];
  const float* conv_b = (const float*)d_in[3];
  const float* cls_w  = (const float*)d_in[4];
  const float* cls_b  = (const float*)d_in[5];
  const float* bbox_w = (const float*)d_in[6];
  const float* bbox_b = (const float*)d_in[7];
  float* out = (float*)d_out;
  char*  ws  = (char*)d_ws;
  float* x      = (float*)(ws + X_B);
  float* bbox   = (float*)(ws + BBOX_B);
  float* props  = (float*)(ws + PROPS_B);
  unsigned long long* keys  = (unsigned long long*)(ws + KEYS_B);
  unsigned*           rankp = (unsigned*)(ws + RANK_B);
  unsigned long long* skeys = (unsigned long long*)(ws + SKEYS_B);
  float4*             sboxs = (float4*)(ws + SBOX_B);
  unsigned long long* keptw = (unsigned long long*)(ws + KEPT_B);
  unsigned long long* maskp = (unsigned long long*)(ws + MASK_B);
  double*             wdp   = (double*)(ws + WD_B);

  if (ws_size >= (size_t)WS_NEED) {
    hipLaunchKernelGGL(prep_wd_k, dim3(4608), dim3(256), 0, stream, conv_w, wdp);
    hipLaunchKernelGGL(conv3x3_relu_k, dim3(512), dim3(512), 0, stream,
                       feat, wdp, conv_b, x);
    hipLaunchKernelGGL(head1x1_k, dim3(216), dim3(256), 0, stream,
                       x, cls_w, cls_b, bbox_w, bbox_b, out, bbox);
    hipLaunchKernelGGL(proposals_k, dim3(36), dim3(256), 0, stream,
                       bbox, imgsz, out, props, keys, rankp);
    hipLaunchKernelGGL(rank_k, dim3(576), dim3(256), 0, stream, keys, rankp);
    hipLaunchKernelGGL(scatter_k, dim3(36), dim3(256), 0, stream,
                       keys, rankp, props, skeys, sboxs);
    hipLaunchKernelGGL(mask_k, dim3(18, 144), dim3(64), 0, stream, sboxs, maskp);
    hipLaunchKernelGGL(sweep_k, dim3(1), dim3(64), 0, stream, maskp, keptw);
    hipLaunchKernelGGL(outk, dim3(36), dim3(256), 0, stream,
                       skeys, sboxs, keptw, out);
  } else {
    hipLaunchKernelGGL(conv3x3_relu_fb_k, dim3(512), dim3(256), 0, stream,
                       feat, conv_w, conv_b, x);
    hipLaunchKernelGGL(head1x1_k, dim3(216), dim3(256), 0, stream,
                       x, cls_w, cls_b, bbox_w, bbox_b, out, bbox);
    hipLaunchKernelGGL(proposals_k, dim3(36), dim3(256), 0, stream,
                       bbox, imgsz, out, props, keys, rankp);
    hipLaunchKernelGGL(nms_fallback_k, dim3(1), dim3(1024), 0, stream,
                       props, out);
  }
}

// Round 6
// 370.799 us; speedup vs baseline: 1.3813x; 1.0400x over previous
//
#include <hip/hip_runtime.h>
#include <math.h>

// ---------------- workspace layout (bytes) ----------------
#define X_B      0         // 512*1024 f32   = 2,097,152
#define BBOX_B   2097152   // 36*1024 f32    = 147,456
#define PROPS_B  2244608   // 9216 float4    = 147,456
#define KEYS_B   2392064   // 9216 u64       = 73,728
#define RANK_B   2465792   // 9216 u32       = 36,864
#define SKEYS_B  2502656   // 9216 u64       = 73,728
#define SBOX_B   2576384   // 9216 float4    = 147,456
#define MASK_B   2725888   // 9216*144 u64   = 10,616,832 (end 13,342,720)
#define WS_NEED  13400000

// ---- DPP lane exchange (within 16-lane DPP rows; OOB lanes -> 0) ----
// row_shr:1 = lane i gets lane i-1 ; row_shl:1 = lane i gets lane i+1.
__device__ __forceinline__ float dpp_shr1(float x) {
  return __int_as_float(__builtin_amdgcn_update_dpp(
      0, __float_as_int(x), 0x111, 0xF, 0xF, true));
}
__device__ __forceinline__ float dpp_shl1(float x) {
  return __int_as_float(__builtin_amdgcn_update_dpp(
      0, __float_as_int(x), 0x101, 0xF, 0xF, true));
}

// ================= conv 3x3 (256->512, 32x32, pad 1) + ReLU =================
// 512 blocks = (channel-pair cp, image-half himg). 512 threads = 4 K-groups
// (64 ch each) x 128 px-threads (4px x 2ch -> 8 fp64 accs). LDS tile: NO halo
// (pitch 36, 16B-aligned ds_write_b128 staging + ds_read_b128 compute reads);
// +-1 columns come from neighbor lanes via DPP (edge lanes cndmask'd to 0).
// Weights: fp32 scalar loads, software-pipelined one cl ahead (2 SGPR sets),
// converted to fp64 once per (cl,ky). fp64 accumulation throughout.
#define TP  36            // tile pitch (floats), multiple of 4
#define TCH 648           // 18 rows * TP per channel

__global__ __launch_bounds__(512, 4) void conv3x3_relu_k(
    const float* __restrict__ feat, const float* __restrict__ w,
    const float* __restrict__ bias, float* __restrict__ xout)
{
  __shared__ __align__(16) float smf[4][2][2 * TCH];   // 41,472 B
  const int cp = blockIdx.x >> 1, himg = blockIdx.x & 1;
  const int tid = threadIdx.x;
  const int kg = __builtin_amdgcn_readfirstlane(tid >> 7);  // wave-uniform 0..3
  const int t = tid & 127;
  const int h16 = himg << 4;
  const int co0 = cp << 1;
  const int kbase = kg << 6;

  for (int i = tid; i < 4 * 2 * 2 * TCH; i += 512) ((float*)smf)[i] = 0.0f;

  const int yl = t >> 3;            // 0..15 local row
  const int x0 = (t & 7) << 2;      // 0,4,...,28
  double aA[4] = {0,0,0,0}, aB[4] = {0,0,0,0};

  const float4* feat4 = (const float4*)feat;
  // staging: 2ch x 18rows x 8 float4 = 288 float4 over 128 threads -> 3 slots
  float4 pf[3]; int pch[3], prow[3], pc4[3]; bool pok[3];
  #pragma unroll
  for (int k = 0; k < 3; ++k) {
    const int i = t + (k << 7);
    const int ch = i / 144, rem = i - ch * 144;
    const int row = rem >> 3, c4 = rem & 7;
    const int g = h16 - 1 + row;
    pch[k] = ch; prow[k] = row; pc4[k] = c4;
    pok[k] = (i < 288) && ((unsigned)g < 32u);
    pf[k] = pok[k] ? feat4[((kbase + ch) << 8) + (g << 3) + c4]
                   : float4{0.f, 0.f, 0.f, 0.f};
  }

  float fa0[9], fb0[9], fa1[9], fb1[9];
  {
    const float* p = w + co0 * 2304 + kbase * 9;
    #pragma unroll
    for (int q = 0; q < 9; ++q) { fa0[q] = p[q]; fb0[q] = p[q + 2304]; }
  }
  __syncthreads();                  // zero-init visible

  #define CONV_CL(IR, FA, FB)                                                 \
    {                                                                         \
      const float* ir = (IR);                                                 \
      _Pragma("unroll")                                                       \
      for (int ky = 0; ky < 3; ++ky) {                                        \
        const float4 q = *(const float4*)(ir + ky * TP);                      \
        float vl = dpp_shr1(q.w); if (x0 == 0)  vl = 0.f;                     \
        float vr = dpp_shl1(q.x); if (x0 == 28) vr = 0.f;                     \
        const double d0 = (double)vl,  d1 = (double)q.x, d2 = (double)q.y;    \
        const double d3 = (double)q.z, d4 = (double)q.w, d5 = (double)vr;     \
        const double w0 = (double)FA[3*ky],   w1 = (double)FA[3*ky+1];        \
        const double w2 = (double)FA[3*ky+2];                                 \
        const double u0 = (double)FB[3*ky],   u1 = (double)FB[3*ky+1];        \
        const double u2 = (double)FB[3*ky+2];                                 \
        aA[0] += d0*w0 + d1*w1 + d2*w2;  aA[1] += d1*w0 + d2*w1 + d3*w2;      \
        aA[2] += d2*w0 + d3*w1 + d4*w2;  aA[3] += d3*w0 + d4*w1 + d5*w2;      \
        aB[0] += d0*u0 + d1*u1 + d2*u2;  aB[1] += d1*u0 + d2*u1 + d3*u2;      \
        aB[2] += d2*u0 + d3*u1 + d4*u2;  aB[3] += d3*u0 + d4*u1 + d5*u2;      \
      }                                                                       \
    }

  for (int tt = 0; tt < 32; ++tt) {
    const int buf = tt & 1;
    #pragma unroll
    for (int k = 0; k < 3; ++k)
      if (pok[k])
        *(float4*)&smf[kg][buf][pch[k] * TCH + prow[k] * TP + (pc4[k] << 2)] = pf[k];
    if (tt < 31) {
      #pragma unroll
      for (int k = 0; k < 3; ++k) {
        const int g = h16 - 1 + prow[k];
        if (pok[k])
          pf[k] = feat4[((kbase + 2 * (tt + 1) + pch[k]) << 8) + (g << 3) + pc4[k]];
      }
    }
    __syncthreads();                // tile ready (single barrier per tile)
    {                               // prefetch weights for cl=1
      const float* p = w + co0 * 2304 + (kbase + 2 * tt + 1) * 9;
      #pragma unroll
      for (int q = 0; q < 9; ++q) { fa1[q] = p[q]; fb1[q] = p[q + 2304]; }
    }
    CONV_CL(&smf[kg][buf][yl * TP + x0], fa0, fb0);          // cl = 0
    {                               // prefetch weights for next tile's cl=0
      int ci = kbase + 2 * tt + 2; if (ci > 255) ci = 255;   // dummy at end
      const float* p = w + co0 * 2304 + ci * 9;
      #pragma unroll
      for (int q = 0; q < 9; ++q) { fa0[q] = p[q]; fb0[q] = p[q + 2304]; }
    }
    CONV_CL(&smf[kg][buf][TCH + yl * TP + x0], fa1, fb1);    // cl = 1
  }

  // cross-K-group reduce (red overlays smf; all compute reads are done)
  __syncthreads();
  double (*red)[8] = (double(*)[8]) & smf[0][0][0];          // 3*128*8 doubles
  if (kg < 3) {
    double* rp = red[(kg << 7) + t];
    rp[0] = aA[0]; rp[1] = aA[1]; rp[2] = aA[2]; rp[3] = aA[3];
    rp[4] = aB[0]; rp[5] = aB[1]; rp[6] = aB[2]; rp[7] = aB[3];
  }
  __syncthreads();
  if (kg == 3) {
    const double bA = (double)bias[co0], bB = (double)bias[co0 + 1];
    const double* r0 = red[t];
    const double* r1 = red[128 + t];
    const double* r2 = red[256 + t];
    const int y = h16 + yl;
    float4 RA, RB;
    RA.x = (float)fmax(r0[0] + r1[0] + r2[0] + aA[0] + bA, 0.0);
    RA.y = (float)fmax(r0[1] + r1[1] + r2[1] + aA[1] + bA, 0.0);
    RA.z = (float)fmax(r0[2] + r1[2] + r2[2] + aA[2] + bA, 0.0);
    RA.w = (float)fmax(r0[3] + r1[3] + r2[3] + aA[3] + bA, 0.0);
    RB.x = (float)fmax(r0[4] + r1[4] + r2[4] + aB[0] + bB, 0.0);
    RB.y = (float)fmax(r0[5] + r1[5] + r2[5] + aB[1] + bB, 0.0);
    RB.z = (float)fmax(r0[6] + r1[6] + r2[6] + aB[2] + bB, 0.0);
    RB.w = (float)fmax(r0[7] + r1[7] + r2[7] + aB[3] + bB, 0.0);
    *(float4*)&xout[(co0 << 10) + (y << 5) + x0] = RA;
    *(float4*)&xout[((co0 + 1) << 10) + (y << 5) + x0] = RB;
  }
}

// ========== fallback conv (small ws) — R5's version =========================
#define CPITCH 38
#define CCHS   (18 * CPITCH)
__global__ __launch_bounds__(256) void conv3x3_relu_fb_k(
    const float* __restrict__ feat, const float* __restrict__ w,
    const float* __restrict__ bias, float* __restrict__ xout)
{
  __shared__ float il[2][8 * CCHS];
  const int cp = blockIdx.x >> 1, h = blockIdx.x & 1;
  const int tid = threadIdx.x;
  const int h16 = h << 4;
  const int co0 = cp << 1;
  for (int i = tid; i < 8 * CCHS; i += 256) { il[0][i] = 0.0f; il[1][i] = 0.0f; }
  const int yl = tid >> 4;
  const int x0 = (tid & 15) << 1;
  double aA0 = 0.0, aA1 = 0.0, aB0 = 0.0, aB1 = 0.0;
  const float4* feat4 = (const float4*)feat;
  float4 pf[5]; int pch[5], pt[5], pc4[5], pok[5];
  #pragma unroll
  for (int k = 0; k < 5; ++k) {
    const int i = tid + (k << 8);
    const int ch = i / 144, rem = i - ch * 144;
    const int t = rem >> 3, c4 = rem & 7;
    const int g = h16 - 1 + t;
    pch[k] = ch; pt[k] = t; pc4[k] = c4;
    pok[k] = (i < 1152) && ((unsigned)g < 32u);
    pf[k] = pok[k] ? feat4[(ch << 8) + (g << 3) + c4] : float4{0.f,0.f,0.f,0.f};
  }
  __syncthreads();
  for (int cc = 0; cc < 256; cc += 8) {
    const int buf = (cc >> 3) & 1;
    #pragma unroll
    for (int k = 0; k < 5; ++k)
      if (pok[k]) {
        float* p = &il[buf][pch[k] * CCHS + pt[k] * CPITCH + (pc4[k] << 2) + 1];
        p[0] = pf[k].x; p[1] = pf[k].y; p[2] = pf[k].z; p[3] = pf[k].w;
      }
    if (cc + 8 < 256) {
      #pragma unroll
      for (int k = 0; k < 5; ++k) {
        const int g = h16 - 1 + pt[k];
        if (pok[k]) pf[k] = feat4[((cc + 8 + pch[k]) << 8) + (g << 3) + pc4[k]];
      }
    }
    __syncthreads();
    #pragma unroll
    for (int cl = 0; cl < 8; ++cl) {
      const float* wAp = w + co0 * 2304 + (cc + cl) * 9;
      const float* wBp = wAp + 2304;
      double wa[9], wb[9];
      #pragma unroll
      for (int q = 0; q < 9; ++q) { wa[q] = (double)wAp[q]; wb[q] = (double)wBp[q]; }
      const float* ir = &il[buf][cl * CCHS + yl * CPITCH + x0];
      #pragma unroll
      for (int ky = 0; ky < 3; ++ky) {
        const float2 q0 = *(const float2*)(ir + ky * CPITCH);
        const float2 q1 = *(const float2*)(ir + ky * CPITCH + 2);
        const double v0 = (double)q0.x, v1 = (double)q0.y;
        const double v2 = (double)q1.x, v3 = (double)q1.y;
        aA0 += v0 * wa[3*ky+0] + v1 * wa[3*ky+1] + v2 * wa[3*ky+2];
        aA1 += v1 * wa[3*ky+0] + v2 * wa[3*ky+1] + v3 * wa[3*ky+2];
        aB0 += v0 * wb[3*ky+0] + v1 * wb[3*ky+1] + v2 * wb[3*ky+2];
        aB1 += v1 * wb[3*ky+0] + v2 * wb[3*ky+1] + v3 * wb[3*ky+2];
      }
    }
  }
  const double bA = (double)bias[co0], bB = (double)bias[co0 + 1];
  const int y = h16 + yl;
  float2 rA, rB;
  rA.x = (float)fmax(aA0 + bA, 0.0); rA.y = (float)fmax(aA1 + bA, 0.0);
  rB.x = (float)fmax(aB0 + bB, 0.0); rB.y = (float)fmax(aB1 + bB, 0.0);
  *(float2*)&xout[(co0 << 10) + (y << 5) + x0] = rA;
  *(float2*)&xout[((co0 + 1) << 10) + (y << 5) + x0] = rB;
}

// ================= 1x1 heads: cls (18ch -> sigmoid -> out) + bbox (36ch) ====
__global__ __launch_bounds__(256) void head1x1_k(
    const float* __restrict__ x,
    const float* __restrict__ cls_w, const float* __restrict__ cls_b,
    const float* __restrict__ bbox_w, const float* __restrict__ bbox_b,
    float* __restrict__ out, float* __restrict__ bbox_out)
{
  __shared__ float wl[512];
  const int bid = blockIdx.x;
  const int co = bid >> 2;
  const int px = ((bid & 3) << 8) | threadIdx.x;
  const bool is_cls = co < 18;
  const float* wsrc = is_cls ? (cls_w + co * 512) : (bbox_w + (co - 18) * 512);
  for (int i = threadIdx.x; i < 512; i += 256) wl[i] = wsrc[i];
  __syncthreads();
  double acc0 = 0.0, acc1 = 0.0, acc2 = 0.0, acc3 = 0.0;
  #pragma unroll 4
  for (int c = 0; c < 512; c += 4) {
    acc0 += (double)x[((c + 0) << 10) | px] * (double)wl[c + 0];
    acc1 += (double)x[((c + 1) << 10) | px] * (double)wl[c + 1];
    acc2 += (double)x[((c + 2) << 10) | px] * (double)wl[c + 2];
    acc3 += (double)x[((c + 3) << 10) | px] * (double)wl[c + 3];
  }
  double acc = ((acc0 + acc1) + (acc2 + acc3)) +
               (double)(is_cls ? cls_b[co] : bbox_b[co - 18]);
  if (is_cls)
    out[36864 + (co << 10) + px] = (float)(1.0 / (1.0 + exp(-acc)));
  else
    bbox_out[((co - 18) << 10) + px] = (float)acc;
}

// ============ anchors + box decode + clip + key build + rank zero ===========
__global__ __launch_bounds__(256) void proposals_k(
    const float* __restrict__ bbox, const int* __restrict__ imgsz,
    const float* __restrict__ out, float* __restrict__ props,
    unsigned long long* __restrict__ keys, unsigned* __restrict__ rank)
{
  const int r = blockIdx.x * 256 + threadIdx.x;
  if (r >= 9216) return;
  const float4 d = ((const float4*)bbox)[r];
  const int cell = r / 9, a = r - cell * 9;
  const int ix = cell & 31, iy = cell >> 5;
  const int ri = a / 3, si = a - ri * 3;
  const double ratio = (ri == 0) ? 0.5 : (ri == 1 ? 1.0 : 2.0);
  const double scale = (si == 0) ? 128.0 : (si == 1 ? 256.0 : 512.0);
  const double hr = sqrt(ratio), wr = 1.0 / hr;
  const double bx = nearbyint(wr * scale * 0.5);
  const double by = nearbyint(hr * scale * 0.5);
  const double cx = ix * 16.0, cy = iy * 16.0;
  const double w = 2.0 * bx, hh = 2.0 * by;
  const double pcx = (double)d.x * w + cx;
  const double pcy = (double)d.y * hh + cy;
  const double pw = exp((double)d.z) * w;
  const double ph = exp((double)d.w) * hh;
  const double im = (double)imgsz[0];
  float4 o;
  o.x = (float)fmin(fmax(pcx - 0.5 * pw, 0.0), im);
  o.y = (float)fmin(fmax(pcy - 0.5 * ph, 0.0), im);
  o.z = (float)fmin(fmax(pcx + 0.5 * pw, 0.0), im);
  o.w = (float)fmin(fmax(pcy + 0.5 * ph, 0.0), im);
  ((float4*)props)[r] = o;
  const float s = out[36864 + ((2 * (r >> 10) + 1) << 10) + (r & 1023)];
  keys[r] = ((unsigned long long)__float_as_uint(s) << 32) |
            (unsigned)(0x7FFFFFFF - r);
  rank[r] = 0u;
}

// ================= rank sort: rank[j] = #{i : key_i > key_j} ================
__global__ __launch_bounds__(256) void rank_k(
    const unsigned long long* __restrict__ keys, unsigned* __restrict__ rank)
{
  const int jt = blockIdx.x % 36, ic = blockIdx.x / 36;
  const int j = jt * 256 + threadIdx.x;
  const unsigned long long kj = keys[j];
  const int lane = threadIdx.x & 63;
  const int base = ic * 576;
  unsigned lo[9], hi[9];
  #pragma unroll
  for (int rr = 0; rr < 9; ++rr) {
    const unsigned long long k = keys[base + rr * 64 + lane];
    lo[rr] = (unsigned)k; hi[rr] = (unsigned)(k >> 32);
  }
  unsigned cnt = 0;
  #pragma unroll
  for (int rr = 0; rr < 9; ++rr) {
    #pragma unroll
    for (int l = 0; l < 64; ++l) {
      const unsigned llo = (unsigned)__builtin_amdgcn_readlane((int)lo[rr], l);
      const unsigned lhi = (unsigned)__builtin_amdgcn_readlane((int)hi[rr], l);
      const unsigned long long ki = ((unsigned long long)lhi << 32) | llo;
      cnt += (ki > kj) ? 1u : 0u;
    }
  }
  atomicAdd(&rank[j], cnt);
}

// ================= scatter into sorted order ================================
__global__ __launch_bounds__(256) void scatter_k(
    const unsigned long long* __restrict__ keys, const unsigned* __restrict__ rank,
    const float* __restrict__ props, unsigned long long* __restrict__ skeys,
    float4* __restrict__ sboxes)
{
  const int r = blockIdx.x * 256 + threadIdx.x;
  if (r >= 9216) return;
  const unsigned rk = rank[r];
  skeys[rk] = keys[r];
  sboxes[rk] = ((const float4*)props)[r];
}

// ================= suppression bitmask over sorted boxes ====================
__global__ __launch_bounds__(64) void mask_k(
    const float4* __restrict__ sb4, unsigned long long* __restrict__ mask)
{
  const int c = blockIdx.x, W = blockIdx.y;
  const int i_lo = c * 512;
  const int i_hi = min(i_lo + 512, W * 64 + 64);
  if (i_lo >= i_hi) return;
  const int lane = threadIdx.x;
  const float4 bj = sb4[(W << 6) + lane];
  const float areaJ = (bj.z - bj.x) * (bj.w - bj.y);
  for (int i = i_lo; i < i_hi; ++i) {
    const float4 bi = sb4[i];
    const float areaI = (bi.z - bi.x) * (bi.w - bi.y);
    const float ix1 = fmaxf(bj.x, bi.x), iy1 = fmaxf(bj.y, bi.y);
    const float ix2 = fminf(bj.z, bi.z), iy2 = fminf(bj.w, bi.w);
    const float iw = fmaxf(ix2 - ix1, 0.0f), ih = fmaxf(iy2 - iy1, 0.0f);
    const double inter = (double)iw * (double)ih;
    const double uni = (double)areaJ + (double)areaI - inter + 1e-9;
    const unsigned long long bal = __ballot(inter > 0.3 * uni);
    if (lane == 0) mask[(size_t)i * 144 + W] = bal;
  }
}

// ============ sweep (2-word batch) + output scatter, one kernel =============
// 256 threads; wave0 sweeps (alive bitmap in regs: lane l holds words l,
// 64+l, 128+l), then all threads scatter the output. Per round: resolve ALL
// (<=16) alive bits of the first nonzero word; if it drains completely,
// also resolve the next nonzero word (rows fetched speculatively in the same
// latency window, re-validated against the post-word-0 alive state). Exact
// sequential order: word-1 bits come after word-0 bits; >16-bit words are
// revisited before later words are touched.
__global__ __launch_bounds__(256) void sweep_out_k(
    const unsigned long long* __restrict__ mask,
    const unsigned long long* __restrict__ skeys,
    const float4* __restrict__ sboxes,
    float* __restrict__ out)
{
  __shared__ unsigned long long keptS[144];
  const int tid = threadIdx.x;
  if (tid < 64) {
    const int l = tid;
    unsigned long long a0 = ~0ULL, a1 = ~0ULL, a2 = (l < 16) ? ~0ULL : 0ULL;
    unsigned long long k0 = 0, k1 = 0, k2 = 0;
    for (int round = 0; round < 9216; ++round) {
      const unsigned long long f0 = __ballot(a0 != 0ULL);
      const unsigned long long f1 = __ballot(a1 != 0ULL);
      const unsigned long long f2 = __ballot(a2 != 0ULL);
      if (!(f0 | f1 | f2)) break;
      int w0i; unsigned long long wv0;
      if (f0)      { w0i = (int)__builtin_ctzll(f0);       wv0 = __shfl(a0, w0i, 64); }
      else if (f1) { w0i = 64 + (int)__builtin_ctzll(f1);  wv0 = __shfl(a1, w0i - 64, 64); }
      else         { w0i = 128 + (int)__builtin_ctzll(f2); wv0 = __shfl(a2, w0i - 128, 64); }
      unsigned long long g0 = f0, g1 = f1, g2 = f2;
      if (w0i < 64)       g0 &= ~(1ULL << w0i);
      else if (w0i < 128) g1 &= ~(1ULL << (w0i - 64));
      else                g2 &= ~(1ULL << (w0i - 128));
      int w1i = -1; unsigned long long wv1 = 0ULL;
      if (g0)      { w1i = (int)__builtin_ctzll(g0);       wv1 = __shfl(a0, w1i, 64); }
      else if (g1) { w1i = 64 + (int)__builtin_ctzll(g1);  wv1 = __shfl(a1, w1i - 64, 64); }
      else if (g2) { w1i = 128 + (int)__builtin_ctzll(g2); wv1 = __shfl(a2, w1i - 128, 64); }
      const bool do2 = (w1i >= 0) && (__popcll(wv0) <= 16);

      unsigned long long c0 = wv0;
      #pragma unroll
      for (int s = 0; s < 16; ++s) c0 &= (c0 - 1ULL);
      const unsigned long long cm0 = wv0 & ~c0;
      const int n0 = (int)__popcll(cm0);
      unsigned long long c1 = wv1;
      #pragma unroll
      for (int s = 0; s < 16; ++s) c1 &= (c1 - 1ULL);
      const unsigned long long cm1 = do2 ? (wv1 & ~c1) : 0ULL;
      const int n1 = (int)__popcll(cm1);

      int bp0[16], bp1[16];
      { unsigned long long tmp = cm0;
        #pragma unroll
        for (int s = 0; s < 16; ++s) { bp0[s] = tmp ? (int)__builtin_ctzll(tmp) : 0;
                                       tmp &= tmp ? (tmp - 1ULL) : 0ULL; } }
      { unsigned long long tmp = cm1;
        #pragma unroll
        for (int s = 0; s < 16; ++s) { bp1[s] = tmp ? (int)__builtin_ctzll(tmp) : 0;
                                       tmp &= tmp ? (tmp - 1ULL) : 0ULL; } }

      unsigned long long r0a[16], r1a[16], r2a[16];
      unsigned long long r0b[16], r1b[16], r2b[16];
      #pragma unroll
      for (int s = 0; s < 16; ++s) {
        if (s < n0) {
          const size_t base = ((size_t)(w0i << 6) + (size_t)bp0[s]) * 144;
          r0a[s] = mask[base + l];
          r1a[s] = mask[base + 64 + l];
          r2a[s] = (l < 16) ? mask[base + 128 + l] : 0ULL;
        }
        if (s < n1) {
          const size_t base = ((size_t)(w1i << 6) + (size_t)bp1[s]) * 144;
          r0b[s] = mask[base + l];
          r1b[s] = mask[base + 64 + l];
          r2b[s] = (l < 16) ? mask[base + 128 + l] : 0ULL;
        }
      }
      // ---- resolve word 0 ----
      {
        const int reg = w0i >> 6, off = w0i & 63;
        unsigned long long sup = 0ULL, kb = 0ULL;
        #pragma unroll
        for (int s = 0; s < 16; ++s) {
          if (s < n0) {
            const int b = bp0[s];
            if (!((sup >> b) & 1ULL)) {
              kb |= 1ULL << b;
              unsigned long long v;
              if (reg == 0)      v = __shfl(r0a[s], off, 64);
              else if (reg == 1) v = __shfl(r1a[s], off, 64);
              else               v = __shfl(r2a[s], off, 64);
              sup |= v;
              a0 &= ~r0a[s]; a1 &= ~r1a[s]; a2 &= ~r2a[s];
            }
          }
        }
        if (l == off) { if (reg == 0) k0 |= kb; else if (reg == 1) k1 |= kb; else k2 |= kb; }
      }
      // ---- resolve word 1 (re-validated against current alive) ----
      if (do2) {
        const int reg = w1i >> 6, off = w1i & 63;
        unsigned long long live;
        if (reg == 0)      live = __shfl(a0, off, 64);
        else if (reg == 1) live = __shfl(a1, off, 64);
        else               live = __shfl(a2, off, 64);
        unsigned long long sup = 0ULL, kb = 0ULL;
        #pragma unroll
        for (int s = 0; s < 16; ++s) {
          if (s < n1) {
            const int b = bp1[s];
            if (((live >> b) & 1ULL) && !((sup >> b) & 1ULL)) {
              kb |= 1ULL << b;
              unsigned long long v;
              if (reg == 0)      v = __shfl(r0b[s], off, 64);
              else if (reg == 1) v = __shfl(r1b[s], off, 64);
              else               v = __shfl(r2b[s], off, 64);
              sup |= v;
              a0 &= ~r0b[s]; a1 &= ~r1b[s]; a2 &= ~r2b[s];
            }
          }
        }
        if (l == off) { if (reg == 0) k0 |= kb; else if (reg == 1) k1 |= kb; else k2 |= kb; }
      }
    }
    keptS[l] = k0; keptS[64 + l] = k1; if (l < 16) keptS[128 + l] = k2;
  }
  __syncthreads();
  for (int i = tid; i < 9216; i += 256) {
    const unsigned long long key = skeys[i];
    const int orig = 0x7FFFFFFF - (int)(unsigned)(key & 0xFFFFFFFFULL);
    const bool kp = (keptS[i >> 6] >> (i & 63)) & 1ULL;
    float4 ob = sboxes[i];
    if (!kp) { ob.x = 0.f; ob.y = 0.f; ob.z = 0.f; ob.w = 0.f; }
    ((float4*)out)[orig] = ob;
    out[55296 + orig] = kp ? 1.0f : 0.0f;
  }
}

// ================= fallback NMS (small ws) ==================================
__global__ __launch_bounds__(1024) void nms_fallback_k(
    const float* __restrict__ props, float* __restrict__ out)
{
  __shared__ unsigned long long wmax[16];
  __shared__ float4 curBoxS;
  const int tid = threadIdx.x, wid = tid >> 6, lane = tid & 63;
  unsigned long long key[9];
  float4 box[9];
  #pragma unroll
  for (int j = 0; j < 9; ++j) {
    const int r = tid + (j << 10);
    box[j] = ((const float4*)props)[r];
    const float s = out[36864 + ((2 * (r >> 10) + 1) << 10) + (r & 1023)];
    key[j] = ((unsigned long long)__float_as_uint(s) << 32) |
             (unsigned)(0x7FFFFFFF - r);
  }
  unsigned kept = 0;
  for (;;) {
    unsigned long long m = key[0];
    #pragma unroll
    for (int j = 1; j < 9; ++j) m = key[j] > m ? key[j] : m;
    #pragma unroll
    for (int off = 32; off; off >>= 1) {
      const unsigned long long o = __shfl_down(m, off, 64);
      if (o > m) m = o;
    }
    if (lane == 0) wmax[wid] = m;
    __syncthreads();
    unsigned long long K = wmax[0];
    #pragma unroll
    for (int wv = 1; wv < 16; ++wv) { const unsigned long long t = wmax[wv]; if (t > K) K = t; }
    if (K == 0) break;
    #pragma unroll
    for (int j = 0; j < 9; ++j)
      if (key[j] == K) { curBoxS = box[j]; key[j] = 0; kept |= 1u << j; }
    __syncthreads();
    const float4 cb = curBoxS;
    const float areaC = (cb.z - cb.x) * (cb.w - cb.y);
    #pragma unroll
    for (int j = 0; j < 9; ++j) {
      if (key[j]) {
        const float4 b = box[j];
        const float ix1 = fmaxf(b.x, cb.x), iy1 = fmaxf(b.y, cb.y);
        const float ix2 = fminf(b.z, cb.z), iy2 = fminf(b.w, cb.w);
        const float iw = fmaxf(ix2 - ix1, 0.0f), ih = fmaxf(iy2 - iy1, 0.0f);
        const float areaB = (b.z - b.x) * (b.w - b.y);
        const double inter = (double)iw * (double)ih;
        const double uni = (double)areaB + (double)areaC - inter + 1e-9;
        if (inter > 0.3 * uni) key[j] = 0;
      }
    }
    __syncthreads();
  }
  #pragma unroll
  for (int j = 0; j < 9; ++j) {
    const int r = tid + (j << 10);
    const bool kp = (kept >> j) & 1u;
    float4 ob = box[j];
    if (!kp) { ob.x = 0.f; ob.y = 0.f; ob.z = 0.f; ob.w = 0.f; }
    ((float4*)out)[r] = ob;
    out[55296 + r] = kp ? 1.0f : 0.0f;
  }
}

// ============================================================================
extern "C" void kernel_launch(void* const* d_in, const int* in_sizes, int n_in,
                              void* d_out, int out_size, void* d_ws, size_t ws_size,
                              hipStream_t stream)
{
  const float* feat   = (const float*)d_in[0];
  const int*   imgsz  = (const int*)d_in[1];
  const float* conv_w = (const float*)d_in[2];
  const float* conv_b = (const float*)d_in[3];
  const float* cls_w  = (const float*)d_in[4];
  const float* cls_b  = (const float*)d_in[5];
  const float* bbox_w = (const float*)d_in[6];
  const float* bbox_b = (const float*)d_in[7];
  float* out = (float*)d_out;
  char*  ws  = (char*)d_ws;
  float* x      = (float*)(ws + X_B);
  float* bbox   = (float*)(ws + BBOX_B);
  float* props  = (float*)(ws + PROPS_B);
  unsigned long long* keys  = (unsigned long long*)(ws + KEYS_B);
  unsigned*           rankp = (unsigned*)(ws + RANK_B);
  unsigned long long* skeys = (unsigned long long*)(ws + SKEYS_B);
  float4*             sboxs = (float4*)(ws + SBOX_B);
  unsigned long long* maskp = (unsigned long long*)(ws + MASK_B);

  if (ws_size >= (size_t)WS_NEED) {
    hipLaunchKernelGGL(conv3x3_relu_k, dim3(512), dim3(512), 0, stream,
                       feat, conv_w, conv_b, x);
    hipLaunchKernelGGL(head1x1_k, dim3(216), dim3(256), 0, stream,
                       x, cls_w, cls_b, bbox_w, bbox_b, out, bbox);
    hipLaunchKernelGGL(proposals_k, dim3(36), dim3(256), 0, stream,
                       bbox, imgsz, out, props, keys, rankp);
    hipLaunchKernelGGL(rank_k, dim3(576), dim3(256), 0, stream, keys, rankp);
    hipLaunchKernelGGL(scatter_k, dim3(36), dim3(256), 0, stream,
                       keys, rankp, props, skeys, sboxs);
    hipLaunchKernelGGL(mask_k, dim3(18, 144), dim3(64), 0, stream, sboxs, maskp);
    hipLaunchKernelGGL(sweep_out_k, dim3(1), dim3(256), 0, stream,
                       maskp, skeys, sboxs, out);
  } else {
    hipLaunchKernelGGL(conv3x3_relu_fb_k, dim3(512), dim3(256), 0, stream,
                       feat, conv_w, conv_b, x);
    hipLaunchKernelGGL(head1x1_k, dim3(216), dim3(256), 0, stream,
                       x, cls_w, cls_b, bbox_w, bbox_b, out, bbox);
    hipLaunchKernelGGL(proposals_k, dim3(36), dim3(256), 0, stream,
                       bbox, imgsz, out, props, keys, rankp);
    hipLaunchKernelGGL(nms_fallback_k, dim3(1), dim3(1024), 0, stream,
                       props, out);
  }
}